// Round 17
// baseline (649.125 us; speedup 1.0000x reference)
//
#include <hip/hip_runtime.h>
#include <hip/hip_bf16.h>
#include <math.h>

// Geometry (fixed by the reference)
#define BB   2
#define CC   64
#define HH   192
#define WW   192
#define HW   (HH*WW)          // 36864
#define HALO 3
#define HP   (HH + 2*HALO)    // 198
#define WP   (WW + 2*HALO)    // 198
#define PLANE (HP*WP)         // 39204

typedef __attribute__((ext_vector_type(8))) _Float16 f16x8;
typedef __attribute__((ext_vector_type(8))) unsigned short u16x8;
typedef __attribute__((ext_vector_type(4))) float f32x4;

__device__ __forceinline__ float fast_tanh(float x) {
    float e = __expf(2.f * x);
    return 1.f - 2.f * __builtin_amdgcn_rcpf(e + 1.f);
}

// hp32 layout: [b][c/32][y][x][32ch] fp16 — 64B per (pixel, channel-half).
// Indexed as u16x8 (16B): elem = ((b*2+half)*PLANE + y*WP + x)*4 + chunk,
// chunk = (c%32)/8. Lanes lg=0..3 at the same pixel hit one 64B line.

// ---------------------------------------------------------------------------
// 1x1 conv (64->64) with fused epilogues, split 2-way over outputs.
// MODE 0: out = relu(W @ X) -> PADDED hp32 fp16 layout (64B/px contiguous)
// MODE 1: out = relu(W @ (X * tanh(M)))  -> flat f32 layout
// MODE 2: out = relu(W @ (X * tanh(M))) + Y0+Y1+Y2 -> flat f32 layout
// ---------------------------------------------------------------------------
template<int MODE>
__global__ __launch_bounds__(256) void conv1x1_k(
    const float* __restrict__ X, const float* __restrict__ M2,
    const float* __restrict__ W,
    const float* __restrict__ Y0, const float* __restrict__ Y1,
    const float* __restrict__ Y2,
    float* __restrict__ out)
{
    __shared__ float wl[64*32];   // [c][o_half]
    int tid = threadIdx.x;
    int oh  = blockIdx.y;         // output half (= channel half of hp32)
    #pragma unroll
    for (int n = 0; n < 8; n++) {
        int idx = tid + n*256;            // [0,2048)
        int op  = idx >> 6, c = idx & 63;
        wl[c*32 + op] = W[(size_t)(oh*32 + op)*64 + c];
    }
    __syncthreads();

    int p  = blockIdx.x*256 + tid;   // [0, BB*HW)
    int b  = p / HW;
    int pp = p - b*HW;

    const float* xb = X + (size_t)b*CC*HW + pp;
    const float* mb = (MODE >= 1) ? (M2 + (size_t)b*CC*HW + pp) : nullptr;

    float acc[32];
    #pragma unroll
    for (int o = 0; o < 32; o++) acc[o] = 0.f;

    #pragma unroll 4
    for (int c = 0; c < 64; c++) {
        float xv = xb[(size_t)c*HW];
        if (MODE >= 1) xv *= fast_tanh(mb[(size_t)c*HW]);
        const float4* w4 = (const float4*)(wl + c*32);
        #pragma unroll
        for (int q = 0; q < 8; q++) {
            float4 w = w4[q];
            acc[4*q+0] = fmaf(w.x, xv, acc[4*q+0]);
            acc[4*q+1] = fmaf(w.y, xv, acc[4*q+1]);
            acc[4*q+2] = fmaf(w.z, xv, acc[4*q+2]);
            acc[4*q+3] = fmaf(w.w, xv, acc[4*q+3]);
        }
    }

    if (MODE == 0) {
        int y = pp / WW, x = pp - y*WW;
        u16x8* hp32 = (u16x8*)out;
        size_t base = ((size_t)(b*2 + oh)*PLANE + (size_t)(y+HALO)*WP + (x+HALO))*4;
        #pragma unroll
        for (int gq = 0; gq < 4; gq++) {
            u16x8 v;
            #pragma unroll
            for (int c = 0; c < 8; c++)
                v[c] = __builtin_bit_cast(unsigned short,
                         (_Float16)fmaxf(acc[gq*8+c], 0.f));
            hp32[base + gq] = v;
        }
    } else if (MODE == 1) {
        float* op = out + (size_t)b*CC*HW + (size_t)(oh*32)*HW + pp;
        #pragma unroll
        for (int o = 0; o < 32; o++) op[(size_t)o*HW] = fmaxf(acc[o], 0.f);
    } else {
        float* op = out + (size_t)b*CC*HW + (size_t)(oh*32)*HW + pp;
        size_t gi = (size_t)b*CC*HW + (size_t)(oh*32)*HW + pp;
        #pragma unroll
        for (int o = 0; o < 32; o++) {
            float yv = Y0[gi + (size_t)o*HW] + Y1[gi + (size_t)o*HW] + Y2[gi + (size_t)o*HW];
            op[(size_t)o*HW] = fmaxf(acc[o], 0.f) + yv;
        }
    }
}

// ---------------------------------------------------------------------------
// Pre-bake offset+mask conv weights into MFMA B-fragment order, fp16.
// ---------------------------------------------------------------------------
template<int K>
__global__ __launch_bounds__(256) void make_woffb_k(
    const float* __restrict__ Woff, const float* __restrict__ Wmod,
    f16x8* __restrict__ wbg)
{
    constexpr int KK  = K*K;
    constexpr int NTF = (3*KK + 15)/16;
    int pos = blockIdx.x;
    for (int idx = threadIdx.x; idx < 2*NTF*64; idx += 256) {
        int kk  = idx / (NTF*64);
        int rem = idx - kk*(NTF*64);
        int nt  = rem >> 6;
        int l   = rem & 63;
        int lg  = l >> 4, lr = l & 15;
        int n   = nt*16 + lr;
        f16x8 v;
        #pragma unroll
        for (int j = 0; j < 8; j++) {
            int c = kk*32 + lg*8 + j;
            float w = 0.f;
            if (n < 2*KK)      w = Woff[((size_t)n*CC + c)*KK + pos];
            else if (n < 3*KK) w = Wmod[((size_t)(n - 2*KK)*CC + c)*KK + pos];
            v[j] = (_Float16)w;
        }
        wbg[(size_t)pos*(2*NTF*64) + idx] = v;
    }
}

// ---------------------------------------------------------------------------
// Offset + mask KxK conv as MFMA implicit GEMM (full conv), fp16, hp32 input.
// MT = M-tiles per wave; NS = n-split across blocks; PPR = positions/round.
// A-load: lane addr = ((b*2+kk)*PLANE + rbase + mt*16+lr)*4 + lg (u16x8) —
// same 16-segment footprint as before (layout change is neutral here).
// ---------------------------------------------------------------------------
template<int K, int MT, int NS, int PPR>
__global__ __launch_bounds__(256) void offmod_mfma_k(
    const u16x8* __restrict__ hp32,
    const f16x8* __restrict__ wbg,
    const float* __restrict__ Boff, const float* __restrict__ Bmod,
    float* __restrict__ om)
{
    constexpr int PAD  = K/2;
    constexpr int KK   = K*K;
    constexpr int NTF  = (3*KK + 15)/16;
    constexpr int NT   = NTF/NS;
    constexpr int PBB  = HW/(64*MT);
    constexpr int NBLK = BB*PBB*NS;
    constexpr int ROUNDS = (KK + PPR - 1)/PPR;
    constexpr int WELEM  = PPR*2*NT*64;

    __shared__ f16x8 wl[WELEM];

    int raw = blockIdx.x;
    int swz = (raw & 7)*(NBLK >> 3) + (raw >> 3);
    int ng  = swz % NS;
    int s   = swz / NS;
    int b   = s / PBB;
    int blk = s - b*PBB;

    int tid  = threadIdx.x;
    int wave = tid >> 6;
    int l    = tid & 63;
    int lg   = l >> 4, lr = l & 15;
    int pxw  = blk*(4*MT*16) + wave*(MT*16);
    int y    = pxw / WW, x0 = pxw - y*WW;

    f32x4 acc[MT][NT];
    #pragma unroll
    for (int mt = 0; mt < MT; mt++)
        #pragma unroll
        for (int nt = 0; nt < NT; nt++) acc[mt][nt] = (f32x4)0.f;

    for (int r = 0; r < ROUNDS; r++) {
        __syncthreads();
        #pragma unroll
        for (int ii = 0; ii < (WELEM + 255)/256; ii++) {
            int idx = tid + ii*256;
            if (WELEM % 256 == 0 || idx < WELEM) {
                int pp  = idx / (2*NT*64);
                int rem = idx - pp*(2*NT*64);
                int kk  = rem / (NT*64);
                int rem2= rem - kk*(NT*64);
                int nt  = rem2 >> 6;
                int ll  = rem2 & 63;
                int pos = r*PPR + pp;
                if (pos < KK)
                    wl[idx] = wbg[(size_t)pos*(2*NTF*64)
                                  + (size_t)(kk*NTF + ng*NT + nt)*64 + ll];
            }
        }
        __syncthreads();

        #pragma unroll
        for (int pp = 0; pp < PPR; pp++) {
            int pos = r*PPR + pp;
            if (pos >= KK) break;
            int i = pos / K, j = pos - (pos/K)*K;
            int rbase = (y + HALO - PAD + i)*WP + (x0 + HALO - PAD + j);

            #pragma unroll
            for (int kk = 0; kk < 2; kk++) {
                const u16x8* G = hp32 + ((size_t)(b*2 + kk)*PLANE + rbase)*4 + lg;
                f16x8 a[MT];
                #pragma unroll
                for (int mt = 0; mt < MT; mt++)
                    a[mt] = __builtin_bit_cast(f16x8, G[(size_t)(mt*16 + lr)*4]);
                #pragma unroll
                for (int nt = 0; nt < NT; nt++) {
                    f16x8 bf = wl[((pp*2 + kk)*NT + nt)*64 + l];
                    #pragma unroll
                    for (int mt = 0; mt < MT; mt++)
                        acc[mt][nt] = __builtin_amdgcn_mfma_f32_16x16x32_f16(
                            a[mt], bf, acc[mt][nt], 0, 0, 0);
                }
            }
        }
    }

    #pragma unroll
    for (int nt = 0; nt < NT; nt++) {
        int n = ng*NT*16 + nt*16 + lr;
        if (n < 3*KK) {
            bool is_mask = (n >= 2*KK);
            float bias = is_mask ? Bmod[n - 2*KK] : Boff[n];
            float* dst0 = om + ((size_t)b*3*KK + n)*HW + pxw + lg*4;
            #pragma unroll
            for (int mt = 0; mt < MT; mt++) {
                f32x4 v = acc[mt][nt];
                float v0 = v[0] + bias, v1 = v[1] + bias, v2 = v[2] + bias, v3 = v[3] + bias;
                if (is_mask) {
                    v0 = 2.f * __builtin_amdgcn_rcpf(1.f + __expf(-v0));
                    v1 = 2.f * __builtin_amdgcn_rcpf(1.f + __expf(-v1));
                    v2 = 2.f * __builtin_amdgcn_rcpf(1.f + __expf(-v2));
                    v3 = 2.f * __builtin_amdgcn_rcpf(1.f + __expf(-v3));
                }
                float4 o;
                o.x = v0; o.y = v1; o.z = v2; o.w = v3;
                *reinterpret_cast<float4*>(dst0 + mt*16) = o;
            }
        }
    }
}

// ---------------------------------------------------------------------------
// Pre-bake w_reg [o][c][K][K] into MFMA B-fragment order, fp16.
// ---------------------------------------------------------------------------
template<int K>
__global__ __launch_bounds__(512) void make_wtb_k(
    const float* __restrict__ Wreg, f16x8* __restrict__ wtb)
{
    constexpr int KK = K*K;
    int t   = blockIdx.x;
    int tid = threadIdx.x;
    int kk  = tid >> 8;
    int rem = tid & 255;
    int ot  = rem >> 6;
    int l   = rem & 63;
    int lr  = l & 15, lg = l >> 4;
    int o   = ot*16 + lr;
    f16x8 v;
    #pragma unroll
    for (int j = 0; j < 8; j++) {
        int c = kk*32 + lg*8 + j;
        v[j] = (_Float16)Wreg[((size_t)o*CC + c)*KK + t];
    }
    wtb[(size_t)t*8*64 + (size_t)(kk*4 + ot)*64 + l] = v;
}

// ---------------------------------------------------------------------------
// Deformable sampling + MFMA channel matmul, fp16 hp32 input.
// r17 = r15/16 structure with ONE change: hp32 layout — the 4 lanes (lg)
// of one pixel load consecutive 16B of the same 64B line, so each gather
// instruction touches 16 segments instead of 64 (4x fewer TA cycles).
// Corners at u16x8 offsets 0 / +4 / +WP*4 / +WP*4+4 from one base.
// ---------------------------------------------------------------------------
template<int K>
__global__ __launch_bounds__(256, 8) void deform_mfma_k(
    const u16x8* __restrict__ hp32,
    const float* __restrict__ om,
    const f16x8* __restrict__ wtb,
    float* __restrict__ out)
{
    constexpr int PAD = K/2;
    constexpr int KK  = K*K;
    constexpr int NSB = HW/16;          // 2304 strips per batch
    constexpr int OMW = 3*KK*16;        // om slice floats
    constexpr int RED = 2*64*16;        // reduce buffer floats
    constexpr int SMEM = (OMW > RED ? OMW : RED);
    __shared__ float smem[SMEM];

    int raw = blockIdx.x;               // [0, BB*NSB) = 4608
    int swz = (raw & 7)*((BB*NSB) >> 3) + (raw >> 3);
    int b = swz / NSB, strip = swz - b*NSB;

    int tid  = threadIdx.x;
    int wave = tid >> 6;
    int l    = tid & 63;
    int lg   = l >> 4;
    int lr   = l & 15;
    int th   = wave & 1;                // tap half
    int kkh  = wave >> 1;               // K-chunk half
    int pxbase = strip*16;
    int px   = pxbase + lr;
    int y    = px / WW, x = px - y*WW;

    // ---- bulk om stage: [3KK][16] slice ----
    {
        const float* ob = om + (size_t)b*3*KK*HW + pxbase;
        for (int idx = tid; idx < OMW; idx += 256) {
            int ch = idx >> 4, pl = idx & 15;
            smem[idx] = ob[(size_t)ch*HW + pl];
        }
    }
    __syncthreads();

    int t0 = (KK*th)/2, t1 = (KK*(th+1))/2;

    f32x4 acc[4];
    #pragma unroll
    for (int ot = 0; ot < 4; ot++) acc[ot] = (f32x4)0.f;

    // this wave+lane's channel-half plane + chunk (channels kkh*32+lg*8..+7)
    const u16x8* hb = hp32 + ((size_t)(b*2 + kkh)*PLANE)*4 + lg;

    #pragma unroll 2
    for (int t = t0; t < t1; t++) {
        int i = t / K, j = t - (t/K)*K;
        float offy = smem[(2*t  )*16 + lr];
        float offx = smem[(2*t+1)*16 + lr];
        float mk   = smem[(2*KK+t)*16 + lr];

        float py = (float)(y - PAD + i) + offy;
        float pxf= (float)(x - PAD + j) + offx;
        float fy = floorf(py), fx = floorf(pxf);
        float wy1 = py - fy, wx1 = pxf - fx;
        float wy0 = 1.f - wy1, wx0 = 1.f - wx1;
        int iy0 = (int)fy, ix0 = (int)fx;

        // clamp to [-1,192]: clamped loads land in the zero halo.
        int Y0 = min(max(iy0, -1), HH) + HALO;   // [2,195]
        int X0 = min(max(ix0, -1), WW) + HALO;   // [2,195]

        _Float16 h00 = (_Float16)(wy0*wx0*mk);
        _Float16 h01 = (_Float16)(wy0*wx1*mk);
        _Float16 h10 = (_Float16)(wy1*wx0*mk);
        _Float16 h11 = (_Float16)(wy1*wx1*mk);

        // 4 coalesced-line gathers from ONE base (u16x8 offsets 0/4/WP*4/WP*4+4)
        const u16x8* G = hb + (size_t)(Y0*WP + X0)*4;
        f16x8 c0 = __builtin_bit_cast(f16x8, G[0]);
        f16x8 c1 = __builtin_bit_cast(f16x8, G[4]);
        f16x8 c2 = __builtin_bit_cast(f16x8, G[WP*4]);
        f16x8 c3 = __builtin_bit_cast(f16x8, G[WP*4 + 4]);

        // packed fp16 bilinear blend -> A-fragment directly
        f16x8 s = c0*h00 + c1*h01 + c2*h10 + c3*h11;

        const f16x8* bp = wtb + (size_t)t*8*64 + l;
        #pragma unroll
        for (int ot = 0; ot < 4; ot++) {
            acc[ot] = __builtin_amdgcn_mfma_f32_16x16x32_f16(
                s, bp[(size_t)(kkh*4 + ot)*64], acc[ot], 0, 0, 0);
        }
    }

    // ---- two-stage reduce: kkh pairs, then th pairs (smem reused) ----
    __syncthreads();   // all waves done reading om slice
    float (*red)[64][16] = (float (*)[64][16])smem;   // [th][o][px]
    if (kkh == 1) {
        #pragma unroll
        for (int ot = 0; ot < 4; ot++)
            *reinterpret_cast<f32x4*>(&red[th][ot*16 + lr][lg*4]) = acc[ot];
    }
    __syncthreads();
    if (kkh == 0) {
        #pragma unroll
        for (int ot = 0; ot < 4; ot++)
            acc[ot] += *reinterpret_cast<const f32x4*>(&red[th][ot*16 + lr][lg*4]);
    }
    __syncthreads();
    if (kkh == 0 && th == 1) {
        #pragma unroll
        for (int ot = 0; ot < 4; ot++)
            *reinterpret_cast<f32x4*>(&red[0][ot*16 + lr][lg*4]) = acc[ot];
    }
    __syncthreads();
    if (kkh == 0 && th == 0) {
        float* ob = out + (size_t)b*CC*HW + pxbase + lg*4;
        #pragma unroll
        for (int ot = 0; ot < 4; ot++) {
            f32x4 rr = *reinterpret_cast<const f32x4*>(&red[0][ot*16 + lr][lg*4]);
            rr += acc[ot];
            float4 v;
            v.x = rr[0]; v.y = rr[1]; v.z = rr[2]; v.w = rr[3];
            *reinterpret_cast<float4*>(ob + (size_t)(ot*16 + lr)*HW) = v;
        }
    }
}

// ---------------------------------------------------------------------------
// Launch. Workspace:
//   hp32: 2*2*PLANE*64B          = ~10.0 MB   (fp16 32ch-interleaved padded h)
//   om : 2*3*49*HW  f32          = ~43.4 MB   (reused as u after last deform)
//   mm : 2*64*HW    f32          = ~18.9 MB
//   sm : 2*64*HW    f32          = ~18.9 MB
//   wtb: 49*512 f16x8            = ~0.4 MB
//   wbg: 49*2*10*64 f16x8        = ~1.0 MB
// ---------------------------------------------------------------------------
extern "C" void kernel_launch(void* const* d_in, const int* in_sizes, int n_in,
                              void* d_out, int out_size, void* d_ws, size_t ws_size,
                              hipStream_t stream)
{
    const float* x_max      = (const float*)d_in[0];
    const float* x_mid      = (const float*)d_in[1];
    const float* x_small    = (const float*)d_in[2];
    const float* w_pre_max  = (const float*)d_in[3];
    const float* w_off_max  = (const float*)d_in[4];
    const float* b_off_max  = (const float*)d_in[5];
    const float* w_mod_max  = (const float*)d_in[6];
    const float* b_mod_max  = (const float*)d_in[7];
    const float* w_reg_max  = (const float*)d_in[8];
    const float* w_pre_mid  = (const float*)d_in[9];
    const float* w_off_mid  = (const float*)d_in[10];
    const float* b_off_mid  = (const float*)d_in[11];
    const float* w_mod_mid  = (const float*)d_in[12];
    const float* b_mod_mid  = (const float*)d_in[13];
    const float* w_reg_mid  = (const float*)d_in[14];
    const float* w_pre_small= (const float*)d_in[15];
    const float* w_off_small= (const float*)d_in[16];
    const float* b_off_small= (const float*)d_in[17];
    const float* w_mod_small= (const float*)d_in[18];
    const float* b_mod_small= (const float*)d_in[19];
    const float* w_reg_small= (const float*)d_in[20];
    const float* w1         = (const float*)d_in[21];
    const float* w2         = (const float*)d_in[22];

    float* out = (float*)d_out;
    float* ws  = (float*)d_ws;
    u16x8* hp32= (u16x8*)ws;
    float* om  = ws + (size_t)BB*8*PLANE*4;   // hp32 = BB*2*PLANE*64B (same bytes)
    float* mm  = om + (size_t)BB*3*49*HW;
    float* sm  = mm + (size_t)BB*CC*HW;
    f16x8* wtb = (f16x8*)(sm + (size_t)BB*CC*HW);
    f16x8* wbg = wtb + (size_t)49*8*64;
    float* u   = om;   // om dead after last deform

    hipMemsetAsync(hp32, 0, (size_t)BB*8*PLANE*sizeof(u16x8), stream);

    const int npix_blocks = (BB*HW)/256;   // 288
    const int dfm_blocks  = BB*(HW/16);    // 4608

    const int off7_blocks = BB*(HW/128)*2; // MT=2, NS=2 -> 1152
    const int off5_blocks = BB*(HW/64);    // MT=1, NS=1 -> 1152
    const int off3_blocks = BB*(HW/128);   // MT=2, NS=1 -> 576

    // ---- max branch (K=7) -> a in d_out
    conv1x1_k<0><<<dim3(npix_blocks,2), 256, 0, stream>>>(x_max, nullptr, w_pre_max,
                                                  nullptr, nullptr, nullptr, (float*)hp32);
    make_woffb_k<7><<<49, 256, 0, stream>>>(w_off_max, w_mod_max, wbg);
    offmod_mfma_k<7,2,2,2><<<off7_blocks, 256, 0, stream>>>(hp32, wbg, b_off_max, b_mod_max, om);
    make_wtb_k<7><<<49, 512, 0, stream>>>(w_reg_max, wtb);
    deform_mfma_k<7><<<dfm_blocks, 256, 0, stream>>>(hp32, om, wtb, out);

    // ---- mid branch (K=5) -> mm
    conv1x1_k<0><<<dim3(npix_blocks,2), 256, 0, stream>>>(x_mid, nullptr, w_pre_mid,
                                                  nullptr, nullptr, nullptr, (float*)hp32);
    make_woffb_k<5><<<25, 256, 0, stream>>>(w_off_mid, w_mod_mid, wbg);
    offmod_mfma_k<5,1,1,2><<<off5_blocks, 256, 0, stream>>>(hp32, wbg, b_off_mid, b_mod_mid, om);
    make_wtb_k<5><<<25, 512, 0, stream>>>(w_reg_mid, wtb);
    deform_mfma_k<5><<<dfm_blocks, 256, 0, stream>>>(hp32, om, wtb, mm);

    // ---- small branch (K=3) -> sm
    conv1x1_k<0><<<dim3(npix_blocks,2), 256, 0, stream>>>(x_small, nullptr, w_pre_small,
                                                  nullptr, nullptr, nullptr, (float*)hp32);
    make_woffb_k<3><<<9, 256, 0, stream>>>(w_off_small, w_mod_small, wbg);
    offmod_mfma_k<3,2,1,3><<<off3_blocks, 256, 0, stream>>>(hp32, wbg, b_off_small, b_mod_small, om);
    make_wtb_k<3><<<9, 512, 0, stream>>>(w_reg_small, wtb);
    deform_mfma_k<3><<<dfm_blocks, 256, 0, stream>>>(hp32, om, wtb, sm);

    // ---- combine
    conv1x1_k<1><<<dim3(npix_blocks,2), 256, 0, stream>>>(out, mm, w1,
                                                  nullptr, nullptr, nullptr, u);
    conv1x1_k<2><<<dim3(npix_blocks,2), 256, 0, stream>>>(u, sm, w2,
                                                  x_max, x_mid, x_small, out);
}

// Round 18
// 556.928 us; speedup vs baseline: 1.1655x; 1.1655x over previous
//
#include <hip/hip_runtime.h>
#include <hip/hip_bf16.h>
#include <math.h>

// Geometry (fixed by the reference)
#define BB   2
#define CC   64
#define HH   192
#define WW   192
#define HW   (HH*WW)          // 36864
#define HALO 3
#define HP   (HH + 2*HALO)    // 198
#define WP   (WW + 2*HALO)    // 198
#define PLANE (HP*WP)         // 39204

typedef __attribute__((ext_vector_type(8))) _Float16 f16x8;
typedef __attribute__((ext_vector_type(4))) _Float16 f16x4;
typedef __attribute__((ext_vector_type(8))) unsigned short u16x8;
typedef __attribute__((ext_vector_type(4))) float f32x4;

__device__ __forceinline__ float fast_tanh(float x) {
    float e = __expf(2.f * x);
    return 1.f - 2.f * __builtin_amdgcn_rcpf(e + 1.f);
}

// ---------------------------------------------------------------------------
// 1x1 conv (64->64) with fused epilogues, split 2-way over outputs.
// MODE 0: X f32        -> relu(W@X)            -> PADDED fp16 hp8 layout
// MODE 1: X f16, M f16 -> relu(W@(X*tanh(M)))  -> flat f16
// MODE 2: X f16, M f16 -> relu(W@(X*tanh(M))) + Y0+Y1+Y2 -> flat f32 (d_out)
// ---------------------------------------------------------------------------
template<int MODE>
__global__ __launch_bounds__(256) void conv1x1_k(
    const void* __restrict__ Xv, const void* __restrict__ Mv,
    const float* __restrict__ W,
    const float* __restrict__ Y0, const float* __restrict__ Y1,
    const float* __restrict__ Y2,
    void* __restrict__ outv)
{
    __shared__ float wl[64*32];   // [c][o_half]
    int tid = threadIdx.x;
    int oh  = blockIdx.y;         // output half
    #pragma unroll
    for (int n = 0; n < 8; n++) {
        int idx = tid + n*256;            // [0,2048)
        int op  = idx >> 6, c = idx & 63;
        wl[c*32 + op] = W[(size_t)(oh*32 + op)*64 + c];
    }
    __syncthreads();

    int p  = blockIdx.x*256 + tid;   // [0, BB*HW)
    int b  = p / HW;
    int pp = p - b*HW;

    size_t base = (size_t)b*CC*HW + pp;

    float acc[32];
    #pragma unroll
    for (int o = 0; o < 32; o++) acc[o] = 0.f;

    #pragma unroll 4
    for (int c = 0; c < 64; c++) {
        float xv;
        if (MODE == 0) xv = ((const float*)Xv)[base + (size_t)c*HW];
        else           xv = (float)((const _Float16*)Xv)[base + (size_t)c*HW];
        if (MODE >= 1)
            xv *= fast_tanh((float)((const _Float16*)Mv)[base + (size_t)c*HW]);
        const float4* w4 = (const float4*)(wl + c*32);
        #pragma unroll
        for (int q = 0; q < 8; q++) {
            float4 w = w4[q];
            acc[4*q+0] = fmaf(w.x, xv, acc[4*q+0]);
            acc[4*q+1] = fmaf(w.y, xv, acc[4*q+1]);
            acc[4*q+2] = fmaf(w.z, xv, acc[4*q+2]);
            acc[4*q+3] = fmaf(w.w, xv, acc[4*q+3]);
        }
    }

    if (MODE == 0) {
        int y = pp / WW, x = pp - y*WW;
        u16x8* hp8 = (u16x8*)outv;
        #pragma unroll
        for (int gq = 0; gq < 4; gq++) {
            u16x8 v;
            #pragma unroll
            for (int c = 0; c < 8; c++)
                v[c] = __builtin_bit_cast(unsigned short,
                         (_Float16)fmaxf(acc[gq*8+c], 0.f));
            hp8[(size_t)(b*8 + oh*4 + gq)*PLANE + (size_t)(y+HALO)*WP + (x+HALO)] = v;
        }
    } else if (MODE == 1) {
        _Float16* op = (_Float16*)outv + base + (size_t)(oh*32)*HW;
        #pragma unroll
        for (int o = 0; o < 32; o++)
            op[(size_t)o*HW] = (_Float16)fmaxf(acc[o], 0.f);
    } else {
        float* op = (float*)outv + base + (size_t)(oh*32)*HW;
        size_t gi = base + (size_t)(oh*32)*HW;
        #pragma unroll
        for (int o = 0; o < 32; o++) {
            float yv = Y0[gi + (size_t)o*HW] + Y1[gi + (size_t)o*HW] + Y2[gi + (size_t)o*HW];
            op[(size_t)o*HW] = fmaxf(acc[o], 0.f) + yv;
        }
    }
}

// ---------------------------------------------------------------------------
// Pre-bake offset+mask conv weights into MFMA B-fragment order, fp16.
// ---------------------------------------------------------------------------
template<int K>
__global__ __launch_bounds__(256) void make_woffb_k(
    const float* __restrict__ Woff, const float* __restrict__ Wmod,
    f16x8* __restrict__ wbg)
{
    constexpr int KK  = K*K;
    constexpr int NTF = (3*KK + 15)/16;
    int pos = blockIdx.x;
    for (int idx = threadIdx.x; idx < 2*NTF*64; idx += 256) {
        int kk  = idx / (NTF*64);
        int rem = idx - kk*(NTF*64);
        int nt  = rem >> 6;
        int l   = rem & 63;
        int lg  = l >> 4, lr = l & 15;
        int n   = nt*16 + lr;
        f16x8 v;
        #pragma unroll
        for (int j = 0; j < 8; j++) {
            int c = kk*32 + lg*8 + j;
            float w = 0.f;
            if (n < 2*KK)      w = Woff[((size_t)n*CC + c)*KK + pos];
            else if (n < 3*KK) w = Wmod[((size_t)(n - 2*KK)*CC + c)*KK + pos];
            v[j] = (_Float16)w;
        }
        wbg[(size_t)pos*(2*NTF*64) + idx] = v;
    }
}

// ---------------------------------------------------------------------------
// Offset + mask KxK conv as MFMA implicit GEMM (full conv), fp16, hp8 input.
// MT = M-tiles per wave; NS = n-split across blocks; PPR = positions/round.
// Stores om as f16.
// ---------------------------------------------------------------------------
template<int K, int MT, int NS, int PPR>
__global__ __launch_bounds__(256) void offmod_mfma_k(
    const u16x8* __restrict__ hp8,
    const f16x8* __restrict__ wbg,
    const float* __restrict__ Boff, const float* __restrict__ Bmod,
    _Float16* __restrict__ om)
{
    constexpr int PAD  = K/2;
    constexpr int KK   = K*K;
    constexpr int NTF  = (3*KK + 15)/16;
    constexpr int NT   = NTF/NS;
    constexpr int PBB  = HW/(64*MT);
    constexpr int NBLK = BB*PBB*NS;
    constexpr int ROUNDS = (KK + PPR - 1)/PPR;
    constexpr int WELEM  = PPR*2*NT*64;

    __shared__ f16x8 wl[WELEM];

    int raw = blockIdx.x;
    int swz = (raw & 7)*(NBLK >> 3) + (raw >> 3);
    int ng  = swz % NS;
    int s   = swz / NS;
    int b   = s / PBB;
    int blk = s - b*PBB;

    int tid  = threadIdx.x;
    int wave = tid >> 6;
    int l    = tid & 63;
    int lg   = l >> 4, lr = l & 15;
    int pxw  = blk*(4*MT*16) + wave*(MT*16);
    int y    = pxw / WW, x0 = pxw - y*WW;

    f32x4 acc[MT][NT];
    #pragma unroll
    for (int mt = 0; mt < MT; mt++)
        #pragma unroll
        for (int nt = 0; nt < NT; nt++) acc[mt][nt] = (f32x4)0.f;

    const u16x8* hb = hp8 + (size_t)(b*8)*PLANE;

    for (int r = 0; r < ROUNDS; r++) {
        __syncthreads();
        #pragma unroll
        for (int ii = 0; ii < (WELEM + 255)/256; ii++) {
            int idx = tid + ii*256;
            if (WELEM % 256 == 0 || idx < WELEM) {
                int pp  = idx / (2*NT*64);
                int rem = idx - pp*(2*NT*64);
                int kk  = rem / (NT*64);
                int rem2= rem - kk*(NT*64);
                int nt  = rem2 >> 6;
                int ll  = rem2 & 63;
                int pos = r*PPR + pp;
                if (pos < KK)
                    wl[idx] = wbg[(size_t)pos*(2*NTF*64)
                                  + (size_t)(kk*NTF + ng*NT + nt)*64 + ll];
            }
        }
        __syncthreads();

        #pragma unroll
        for (int pp = 0; pp < PPR; pp++) {
            int pos = r*PPR + pp;
            if (pos >= KK) break;
            int i = pos / K, j = pos - (pos/K)*K;
            int rbase = (y + HALO - PAD + i)*WP + (x0 + HALO - PAD + j);

            #pragma unroll
            for (int kk = 0; kk < 2; kk++) {
                const f16x8* G = (const f16x8*)(hb + (size_t)(kk*4 + lg)*PLANE + rbase);
                f16x8 a[MT];
                #pragma unroll
                for (int mt = 0; mt < MT; mt++) a[mt] = G[mt*16 + lr];
                #pragma unroll
                for (int nt = 0; nt < NT; nt++) {
                    f16x8 bf = wl[((pp*2 + kk)*NT + nt)*64 + l];
                    #pragma unroll
                    for (int mt = 0; mt < MT; mt++)
                        acc[mt][nt] = __builtin_amdgcn_mfma_f32_16x16x32_f16(
                            a[mt], bf, acc[mt][nt], 0, 0, 0);
                }
            }
        }
    }

    #pragma unroll
    for (int nt = 0; nt < NT; nt++) {
        int n = ng*NT*16 + nt*16 + lr;
        if (n < 3*KK) {
            bool is_mask = (n >= 2*KK);
            float bias = is_mask ? Bmod[n - 2*KK] : Boff[n];
            _Float16* dst0 = om + ((size_t)b*3*KK + n)*HW + pxw + lg*4;
            #pragma unroll
            for (int mt = 0; mt < MT; mt++) {
                f32x4 v = acc[mt][nt];
                float v0 = v[0] + bias, v1 = v[1] + bias, v2 = v[2] + bias, v3 = v[3] + bias;
                if (is_mask) {
                    v0 = 2.f * __builtin_amdgcn_rcpf(1.f + __expf(-v0));
                    v1 = 2.f * __builtin_amdgcn_rcpf(1.f + __expf(-v1));
                    v2 = 2.f * __builtin_amdgcn_rcpf(1.f + __expf(-v2));
                    v3 = 2.f * __builtin_amdgcn_rcpf(1.f + __expf(-v3));
                }
                f16x4 o;
                o[0] = (_Float16)v0; o[1] = (_Float16)v1;
                o[2] = (_Float16)v2; o[3] = (_Float16)v3;
                *reinterpret_cast<f16x4*>(dst0 + mt*16) = o;
            }
        }
    }
}

// ---------------------------------------------------------------------------
// Pre-bake w_reg [o][c][K][K] into MFMA B-fragment order, fp16.
// ---------------------------------------------------------------------------
template<int K>
__global__ __launch_bounds__(512) void make_wtb_k(
    const float* __restrict__ Wreg, f16x8* __restrict__ wtb)
{
    constexpr int KK = K*K;
    int t   = blockIdx.x;
    int tid = threadIdx.x;
    int kk  = tid >> 8;
    int rem = tid & 255;
    int ot  = rem >> 6;
    int l   = rem & 63;
    int lr  = l & 15, lg = l >> 4;
    int o   = ot*16 + lr;
    f16x8 v;
    #pragma unroll
    for (int j = 0; j < 8; j++) {
        int c = kk*32 + lg*8 + j;
        v[j] = (_Float16)Wreg[((size_t)o*CC + c)*KK + t];
    }
    wtb[(size_t)t*8*64 + (size_t)(kk*4 + ot)*64 + l] = v;
}

// ---------------------------------------------------------------------------
// Deformable sampling + MFMA channel matmul, fp16 hp8 input (r15 structure).
// 16-px blocks, 4 waves = 2 kkh x 2 th; om (f16) slice in LDS; 4 single-base
// 16B gathers/tap/wave; packed fp16 blend -> MFMA A-frag; two-stage reduce.
// Output stored as f16 [b][64][HW].
// ---------------------------------------------------------------------------
template<int K>
__global__ __launch_bounds__(256, 8) void deform_mfma_k(
    const u16x8* __restrict__ hp8,
    const _Float16* __restrict__ om,
    const f16x8* __restrict__ wtb,
    _Float16* __restrict__ out)
{
    constexpr int PAD = K/2;
    constexpr int KK  = K*K;
    constexpr int NSB = HW/16;          // 2304 strips per batch
    constexpr int OMW = 3*KK*16;        // om slice elems
    constexpr int RED = 2*64*16;        // reduce buffer floats
    constexpr int SMEM = (OMW > RED ? OMW : RED);
    __shared__ float smem[SMEM];

    int raw = blockIdx.x;               // [0, BB*NSB) = 4608
    int swz = (raw & 7)*((BB*NSB) >> 3) + (raw >> 3);
    int b = swz / NSB, strip = swz - b*NSB;

    int tid  = threadIdx.x;
    int wave = tid >> 6;
    int l    = tid & 63;
    int lg   = l >> 4;
    int lr   = l & 15;
    int th   = wave & 1;                // tap half
    int kkh  = wave >> 1;               // K-chunk half
    int pxbase = strip*16;
    int px   = pxbase + lr;
    int y    = px / WW, x = px - y*WW;

    // ---- bulk om stage: [3KK][16] slice (f16 -> f32 in LDS) ----
    {
        const _Float16* ob = om + (size_t)b*3*KK*HW + pxbase;
        for (int idx = tid; idx < OMW; idx += 256) {
            int ch = idx >> 4, pl = idx & 15;
            smem[idx] = (float)ob[(size_t)ch*HW + pl];
        }
    }
    __syncthreads();

    int t0 = (KK*th)/2, t1 = (KK*(th+1))/2;

    f32x4 acc[4];
    #pragma unroll
    for (int ot = 0; ot < 4; ot++) acc[ot] = (f32x4)0.f;

    // this wave+lane's channel-group plane (channels kkh*32 + lg*8 .. +7)
    const u16x8* hb  = hp8 + (size_t)(b*8 + kkh*4 + lg)*PLANE;

    #pragma unroll 2
    for (int t = t0; t < t1; t++) {
        int i = t / K, j = t - (t/K)*K;
        float offy = smem[(2*t  )*16 + lr];
        float offx = smem[(2*t+1)*16 + lr];
        float mk   = smem[(2*KK+t)*16 + lr];

        float py = (float)(y - PAD + i) + offy;
        float pxf= (float)(x - PAD + j) + offx;
        float fy = floorf(py), fx = floorf(pxf);
        float wy1 = py - fy, wx1 = pxf - fx;
        float wy0 = 1.f - wy1, wx0 = 1.f - wx1;
        int iy0 = (int)fy, ix0 = (int)fx;

        // clamp to [-1,192]: clamped loads land in the zero halo.
        int Y0 = min(max(iy0, -1), HH) + HALO;   // [2,195]
        int X0 = min(max(ix0, -1), WW) + HALO;   // [2,195]

        _Float16 h00 = (_Float16)(wy0*wx0*mk);
        _Float16 h01 = (_Float16)(wy0*wx1*mk);
        _Float16 h10 = (_Float16)(wy1*wx0*mk);
        _Float16 h11 = (_Float16)(wy1*wx1*mk);

        // 4 gathers from ONE base address (imm offsets 0,16,WP*16,WP*16+16)
        const u16x8* G = hb + (size_t)(Y0*WP + X0);
        f16x8 c0 = __builtin_bit_cast(f16x8, G[0]);
        f16x8 c1 = __builtin_bit_cast(f16x8, G[1]);
        f16x8 c2 = __builtin_bit_cast(f16x8, G[WP]);
        f16x8 c3 = __builtin_bit_cast(f16x8, G[WP+1]);

        // packed fp16 bilinear blend -> A-fragment directly
        f16x8 s = c0*h00 + c1*h01 + c2*h10 + c3*h11;

        const f16x8* bp = wtb + (size_t)t*8*64 + l;
        #pragma unroll
        for (int ot = 0; ot < 4; ot++) {
            acc[ot] = __builtin_amdgcn_mfma_f32_16x16x32_f16(
                s, bp[(size_t)(kkh*4 + ot)*64], acc[ot], 0, 0, 0);
        }
    }

    // ---- two-stage reduce: kkh pairs, then th pairs (smem reused) ----
    __syncthreads();   // all waves done reading om slice
    float (*red)[64][16] = (float (*)[64][16])smem;   // [th][o][px]
    if (kkh == 1) {
        #pragma unroll
        for (int ot = 0; ot < 4; ot++)
            *reinterpret_cast<f32x4*>(&red[th][ot*16 + lr][lg*4]) = acc[ot];
    }
    __syncthreads();
    if (kkh == 0) {
        #pragma unroll
        for (int ot = 0; ot < 4; ot++)
            acc[ot] += *reinterpret_cast<const f32x4*>(&red[th][ot*16 + lr][lg*4]);
    }
    __syncthreads();
    if (kkh == 0 && th == 1) {
        #pragma unroll
        for (int ot = 0; ot < 4; ot++)
            *reinterpret_cast<f32x4*>(&red[0][ot*16 + lr][lg*4]) = acc[ot];
    }
    __syncthreads();
    if (kkh == 0 && th == 0) {
        _Float16* ob = out + (size_t)b*CC*HW + pxbase + lg*4;
        #pragma unroll
        for (int ot = 0; ot < 4; ot++) {
            f32x4 rr = *reinterpret_cast<const f32x4*>(&red[0][ot*16 + lr][lg*4]);
            rr += acc[ot];
            f16x4 v;
            v[0] = (_Float16)rr[0]; v[1] = (_Float16)rr[1];
            v[2] = (_Float16)rr[2]; v[3] = (_Float16)rr[3];
            *reinterpret_cast<f16x4*>(ob + (size_t)(ot*16 + lr)*HW) = v;
        }
    }
}

// ---------------------------------------------------------------------------
// Launch. Workspace (bytes):
//   hp8: BB*8*PLANE*16B          = ~10.0 MB  (fp16 interleaved padded h)
//   om : BB*3*49*HW*2B           = ~21.7 MB  (f16)
//   aa : BB*CC*HW*2B             = ~9.4 MB   (f16 branch-max output)
//   mm : BB*CC*HW*2B             = ~9.4 MB
//   sm : BB*CC*HW*2B             = ~9.4 MB
//   u  : BB*CC*HW*2B             = ~9.4 MB   (f16 combine intermediate)
//   wtb/wbg f16                  = ~1.4 MB
// ---------------------------------------------------------------------------
extern "C" void kernel_launch(void* const* d_in, const int* in_sizes, int n_in,
                              void* d_out, int out_size, void* d_ws, size_t ws_size,
                              hipStream_t stream)
{
    const float* x_max      = (const float*)d_in[0];
    const float* x_mid      = (const float*)d_in[1];
    const float* x_small    = (const float*)d_in[2];
    const float* w_pre_max  = (const float*)d_in[3];
    const float* w_off_max  = (const float*)d_in[4];
    const float* b_off_max  = (const float*)d_in[5];
    const float* w_mod_max  = (const float*)d_in[6];
    const float* b_mod_max  = (const float*)d_in[7];
    const float* w_reg_max  = (const float*)d_in[8];
    const float* w_pre_mid  = (const float*)d_in[9];
    const float* w_off_mid  = (const float*)d_in[10];
    const float* b_off_mid  = (const float*)d_in[11];
    const float* w_mod_mid  = (const float*)d_in[12];
    const float* b_mod_mid  = (const float*)d_in[13];
    const float* w_reg_mid  = (const float*)d_in[14];
    const float* w_pre_small= (const float*)d_in[15];
    const float* w_off_small= (const float*)d_in[16];
    const float* b_off_small= (const float*)d_in[17];
    const float* w_mod_small= (const float*)d_in[18];
    const float* b_mod_small= (const float*)d_in[19];
    const float* w_reg_small= (const float*)d_in[20];
    const float* w1         = (const float*)d_in[21];
    const float* w2         = (const float*)d_in[22];

    float* out = (float*)d_out;
    char*  ws  = (char*)d_ws;

    u16x8*    hp8 = (u16x8*)ws;                       ws += (size_t)BB*8*PLANE*16;
    _Float16* om  = (_Float16*)ws;                    ws += (size_t)BB*3*49*HW*2;
    _Float16* aa  = (_Float16*)ws;                    ws += (size_t)BB*CC*HW*2;
    _Float16* mm  = (_Float16*)ws;                    ws += (size_t)BB*CC*HW*2;
    _Float16* sm  = (_Float16*)ws;                    ws += (size_t)BB*CC*HW*2;
    _Float16* u   = (_Float16*)ws;                    ws += (size_t)BB*CC*HW*2;
    f16x8*    wtb = (f16x8*)ws;                       ws += (size_t)49*8*64*16;
    f16x8*    wbg = (f16x8*)ws;

    hipMemsetAsync(hp8, 0, (size_t)BB*8*PLANE*16, stream);

    const int npix_blocks = (BB*HW)/256;   // 288
    const int dfm_blocks  = BB*(HW/16);    // 4608

    const int off7_blocks = BB*(HW/128)*2; // MT=2, NS=2 -> 1152
    const int off5_blocks = BB*(HW/64);    // MT=1, NS=1 -> 1152
    const int off3_blocks = BB*(HW/128);   // MT=2, NS=1 -> 576

    // ---- max branch (K=7) -> aa (f16)
    conv1x1_k<0><<<dim3(npix_blocks,2), 256, 0, stream>>>(x_max, nullptr, w_pre_max,
                                                  nullptr, nullptr, nullptr, hp8);
    make_woffb_k<7><<<49, 256, 0, stream>>>(w_off_max, w_mod_max, wbg);
    offmod_mfma_k<7,2,2,2><<<off7_blocks, 256, 0, stream>>>(hp8, wbg, b_off_max, b_mod_max, om);
    make_wtb_k<7><<<49, 512, 0, stream>>>(w_reg_max, wtb);
    deform_mfma_k<7><<<dfm_blocks, 256, 0, stream>>>(hp8, om, wtb, aa);

    // ---- mid branch (K=5) -> mm (f16)
    conv1x1_k<0><<<dim3(npix_blocks,2), 256, 0, stream>>>(x_mid, nullptr, w_pre_mid,
                                                  nullptr, nullptr, nullptr, hp8);
    make_woffb_k<5><<<25, 256, 0, stream>>>(w_off_mid, w_mod_mid, wbg);
    offmod_mfma_k<5,1,1,2><<<off5_blocks, 256, 0, stream>>>(hp8, wbg, b_off_mid, b_mod_mid, om);
    make_wtb_k<5><<<25, 512, 0, stream>>>(w_reg_mid, wtb);
    deform_mfma_k<5><<<dfm_blocks, 256, 0, stream>>>(hp8, om, wtb, mm);

    // ---- small branch (K=3) -> sm (f16)
    conv1x1_k<0><<<dim3(npix_blocks,2), 256, 0, stream>>>(x_small, nullptr, w_pre_small,
                                                  nullptr, nullptr, nullptr, hp8);
    make_woffb_k<3><<<9, 256, 0, stream>>>(w_off_small, w_mod_small, wbg);
    offmod_mfma_k<3,2,1,3><<<off3_blocks, 256, 0, stream>>>(hp8, wbg, b_off_small, b_mod_small, om);
    make_wtb_k<3><<<9, 512, 0, stream>>>(w_reg_small, wtb);
    deform_mfma_k<3><<<dfm_blocks, 256, 0, stream>>>(hp8, om, wtb, sm);

    // ---- combine (f16 in, f16 mid, f32 final)
    conv1x1_k<1><<<dim3(npix_blocks,2), 256, 0, stream>>>(aa, mm, w1,
                                                  nullptr, nullptr, nullptr, u);
    conv1x1_k<2><<<dim3(npix_blocks,2), 256, 0, stream>>>(u, sm, w2,
                                                  x_max, x_mid, x_small, out);
}

// Round 19
// 554.638 us; speedup vs baseline: 1.1704x; 1.0041x over previous
//
#include <hip/hip_runtime.h>
#include <hip/hip_bf16.h>
#include <math.h>

// Geometry (fixed by the reference)
#define BB   2
#define CC   64
#define HH   192
#define WW   192
#define HW   (HH*WW)          // 36864
#define HALO 3
#define HP   (HH + 2*HALO)    // 198
#define WP   (WW + 2*HALO)    // 198
#define PLANE (HP*WP)         // 39204

typedef __attribute__((ext_vector_type(8))) _Float16 f16x8;
typedef __attribute__((ext_vector_type(4))) _Float16 f16x4;
typedef __attribute__((ext_vector_type(8))) unsigned short u16x8;
typedef __attribute__((ext_vector_type(4))) float f32x4;

__device__ __forceinline__ float fast_tanh(float x) {
    float e = __expf(2.f * x);
    return 1.f - 2.f * __builtin_amdgcn_rcpf(e + 1.f);
}

// ---------------------------------------------------------------------------
// 1x1 conv (64->64) with fused epilogues, split 2-way over outputs.
// MODE 0: X f32        -> relu(W@X)            -> PADDED fp16 hp8 layout
// MODE 1: X f16, M f16 -> relu(W@(X*tanh(M)))  -> flat f16
// MODE 2: X f16, M f16 -> relu(W@(X*tanh(M))) + Y0+Y1+Y2 -> flat f32 (d_out)
// ---------------------------------------------------------------------------
template<int MODE>
__global__ __launch_bounds__(256) void conv1x1_k(
    const void* __restrict__ Xv, const void* __restrict__ Mv,
    const float* __restrict__ W,
    const float* __restrict__ Y0, const float* __restrict__ Y1,
    const float* __restrict__ Y2,
    void* __restrict__ outv)
{
    __shared__ float wl[64*32];   // [c][o_half]
    int tid = threadIdx.x;
    int oh  = blockIdx.y;         // output half
    #pragma unroll
    for (int n = 0; n < 8; n++) {
        int idx = tid + n*256;            // [0,2048)
        int op  = idx >> 6, c = idx & 63;
        wl[c*32 + op] = W[(size_t)(oh*32 + op)*64 + c];
    }
    __syncthreads();

    int p  = blockIdx.x*256 + tid;   // [0, BB*HW)
    int b  = p / HW;
    int pp = p - b*HW;

    size_t base = (size_t)b*CC*HW + pp;

    float acc[32];
    #pragma unroll
    for (int o = 0; o < 32; o++) acc[o] = 0.f;

    #pragma unroll 4
    for (int c = 0; c < 64; c++) {
        float xv;
        if (MODE == 0) xv = ((const float*)Xv)[base + (size_t)c*HW];
        else           xv = (float)((const _Float16*)Xv)[base + (size_t)c*HW];
        if (MODE >= 1)
            xv *= fast_tanh((float)((const _Float16*)Mv)[base + (size_t)c*HW]);
        const float4* w4 = (const float4*)(wl + c*32);
        #pragma unroll
        for (int q = 0; q < 8; q++) {
            float4 w = w4[q];
            acc[4*q+0] = fmaf(w.x, xv, acc[4*q+0]);
            acc[4*q+1] = fmaf(w.y, xv, acc[4*q+1]);
            acc[4*q+2] = fmaf(w.z, xv, acc[4*q+2]);
            acc[4*q+3] = fmaf(w.w, xv, acc[4*q+3]);
        }
    }

    if (MODE == 0) {
        int y = pp / WW, x = pp - y*WW;
        u16x8* hp8 = (u16x8*)outv;
        #pragma unroll
        for (int gq = 0; gq < 4; gq++) {
            u16x8 v;
            #pragma unroll
            for (int c = 0; c < 8; c++)
                v[c] = __builtin_bit_cast(unsigned short,
                         (_Float16)fmaxf(acc[gq*8+c], 0.f));
            hp8[(size_t)(b*8 + oh*4 + gq)*PLANE + (size_t)(y+HALO)*WP + (x+HALO)] = v;
        }
    } else if (MODE == 1) {
        _Float16* op = (_Float16*)outv + base + (size_t)(oh*32)*HW;
        #pragma unroll
        for (int o = 0; o < 32; o++)
            op[(size_t)o*HW] = (_Float16)fmaxf(acc[o], 0.f);
    } else {
        float* op = (float*)outv + base + (size_t)(oh*32)*HW;
        size_t gi = base + (size_t)(oh*32)*HW;
        #pragma unroll
        for (int o = 0; o < 32; o++) {
            float yv = Y0[gi + (size_t)o*HW] + Y1[gi + (size_t)o*HW] + Y2[gi + (size_t)o*HW];
            op[(size_t)o*HW] = fmaxf(acc[o], 0.f) + yv;
        }
    }
}

// ---------------------------------------------------------------------------
// Pre-bake offset+mask conv weights into MFMA B-fragment order, fp16.
// ---------------------------------------------------------------------------
template<int K>
__global__ __launch_bounds__(256) void make_woffb_k(
    const float* __restrict__ Woff, const float* __restrict__ Wmod,
    f16x8* __restrict__ wbg)
{
    constexpr int KK  = K*K;
    constexpr int NTF = (3*KK + 15)/16;
    int pos = blockIdx.x;
    for (int idx = threadIdx.x; idx < 2*NTF*64; idx += 256) {
        int kk  = idx / (NTF*64);
        int rem = idx - kk*(NTF*64);
        int nt  = rem >> 6;
        int l   = rem & 63;
        int lg  = l >> 4, lr = l & 15;
        int n   = nt*16 + lr;
        f16x8 v;
        #pragma unroll
        for (int j = 0; j < 8; j++) {
            int c = kk*32 + lg*8 + j;
            float w = 0.f;
            if (n < 2*KK)      w = Woff[((size_t)n*CC + c)*KK + pos];
            else if (n < 3*KK) w = Wmod[((size_t)(n - 2*KK)*CC + c)*KK + pos];
            v[j] = (_Float16)w;
        }
        wbg[(size_t)pos*(2*NTF*64) + idx] = v;
    }
}

// ---------------------------------------------------------------------------
// Offset + mask KxK conv as MFMA implicit GEMM (full conv), fp16, hp8 input.
// MT = M-tiles per wave; NS = n-split across blocks; PPR = positions/round.
// Stores om as f16.
// ---------------------------------------------------------------------------
template<int K, int MT, int NS, int PPR>
__global__ __launch_bounds__(256) void offmod_mfma_k(
    const u16x8* __restrict__ hp8,
    const f16x8* __restrict__ wbg,
    const float* __restrict__ Boff, const float* __restrict__ Bmod,
    _Float16* __restrict__ om)
{
    constexpr int PAD  = K/2;
    constexpr int KK   = K*K;
    constexpr int NTF  = (3*KK + 15)/16;
    constexpr int NT   = NTF/NS;
    constexpr int PBB  = HW/(64*MT);
    constexpr int NBLK = BB*PBB*NS;
    constexpr int ROUNDS = (KK + PPR - 1)/PPR;
    constexpr int WELEM  = PPR*2*NT*64;

    __shared__ f16x8 wl[WELEM];

    int raw = blockIdx.x;
    int swz = (raw & 7)*(NBLK >> 3) + (raw >> 3);
    int ng  = swz % NS;
    int s   = swz / NS;
    int b   = s / PBB;
    int blk = s - b*PBB;

    int tid  = threadIdx.x;
    int wave = tid >> 6;
    int l    = tid & 63;
    int lg   = l >> 4, lr = l & 15;
    int pxw  = blk*(4*MT*16) + wave*(MT*16);
    int y    = pxw / WW, x0 = pxw - y*WW;

    f32x4 acc[MT][NT];
    #pragma unroll
    for (int mt = 0; mt < MT; mt++)
        #pragma unroll
        for (int nt = 0; nt < NT; nt++) acc[mt][nt] = (f32x4)0.f;

    const u16x8* hb = hp8 + (size_t)(b*8)*PLANE;

    for (int r = 0; r < ROUNDS; r++) {
        __syncthreads();
        #pragma unroll
        for (int ii = 0; ii < (WELEM + 255)/256; ii++) {
            int idx = tid + ii*256;
            if (WELEM % 256 == 0 || idx < WELEM) {
                int pp  = idx / (2*NT*64);
                int rem = idx - pp*(2*NT*64);
                int kk  = rem / (NT*64);
                int rem2= rem - kk*(NT*64);
                int nt  = rem2 >> 6;
                int ll  = rem2 & 63;
                int pos = r*PPR + pp;
                if (pos < KK)
                    wl[idx] = wbg[(size_t)pos*(2*NTF*64)
                                  + (size_t)(kk*NTF + ng*NT + nt)*64 + ll];
            }
        }
        __syncthreads();

        #pragma unroll
        for (int pp = 0; pp < PPR; pp++) {
            int pos = r*PPR + pp;
            if (pos >= KK) break;
            int i = pos / K, j = pos - (pos/K)*K;
            int rbase = (y + HALO - PAD + i)*WP + (x0 + HALO - PAD + j);

            #pragma unroll
            for (int kk = 0; kk < 2; kk++) {
                const f16x8* G = (const f16x8*)(hb + (size_t)(kk*4 + lg)*PLANE + rbase);
                f16x8 a[MT];
                #pragma unroll
                for (int mt = 0; mt < MT; mt++) a[mt] = G[mt*16 + lr];
                #pragma unroll
                for (int nt = 0; nt < NT; nt++) {
                    f16x8 bf = wl[((pp*2 + kk)*NT + nt)*64 + l];
                    #pragma unroll
                    for (int mt = 0; mt < MT; mt++)
                        acc[mt][nt] = __builtin_amdgcn_mfma_f32_16x16x32_f16(
                            a[mt], bf, acc[mt][nt], 0, 0, 0);
                }
            }
        }
    }

    #pragma unroll
    for (int nt = 0; nt < NT; nt++) {
        int n = ng*NT*16 + nt*16 + lr;
        if (n < 3*KK) {
            bool is_mask = (n >= 2*KK);
            float bias = is_mask ? Bmod[n - 2*KK] : Boff[n];
            _Float16* dst0 = om + ((size_t)b*3*KK + n)*HW + pxw + lg*4;
            #pragma unroll
            for (int mt = 0; mt < MT; mt++) {
                f32x4 v = acc[mt][nt];
                float v0 = v[0] + bias, v1 = v[1] + bias, v2 = v[2] + bias, v3 = v[3] + bias;
                if (is_mask) {
                    v0 = 2.f * __builtin_amdgcn_rcpf(1.f + __expf(-v0));
                    v1 = 2.f * __builtin_amdgcn_rcpf(1.f + __expf(-v1));
                    v2 = 2.f * __builtin_amdgcn_rcpf(1.f + __expf(-v2));
                    v3 = 2.f * __builtin_amdgcn_rcpf(1.f + __expf(-v3));
                }
                f16x4 o;
                o[0] = (_Float16)v0; o[1] = (_Float16)v1;
                o[2] = (_Float16)v2; o[3] = (_Float16)v3;
                *reinterpret_cast<f16x4*>(dst0 + mt*16) = o;
            }
        }
    }
}

// ---------------------------------------------------------------------------
// Pre-bake w_reg [o][c][K][K] into MFMA B-fragment order, fp16.
// ---------------------------------------------------------------------------
template<int K>
__global__ __launch_bounds__(512) void make_wtb_k(
    const float* __restrict__ Wreg, f16x8* __restrict__ wtb)
{
    constexpr int KK = K*K;
    int t   = blockIdx.x;
    int tid = threadIdx.x;
    int kk  = tid >> 8;
    int rem = tid & 255;
    int ot  = rem >> 6;
    int l   = rem & 63;
    int lr  = l & 15, lg = l >> 4;
    int o   = ot*16 + lr;
    f16x8 v;
    #pragma unroll
    for (int j = 0; j < 8; j++) {
        int c = kk*32 + lg*8 + j;
        v[j] = (_Float16)Wreg[((size_t)o*CC + c)*KK + t];
    }
    wtb[(size_t)t*8*64 + (size_t)(kk*4 + ot)*64 + l] = v;
}

// ---------------------------------------------------------------------------
// Deformable sampling + MFMA channel matmul, fp16 hp8 input.
// r19: block's sampled neighborhood staged into LDS (window [8grp][K+2]
// [16+K+2] of u16x8) — the tap loop samples via ds_read_b128, no global
// latency. Wave-uniform __all(in_window) guard falls back to global
// gathers for any sample outside (edge clamps / large offsets) so the
// kernel is correct for ANY offset values. 16-px blocks, 4 waves =
// 2 kkh x 2 th; om f16 slice in LDS; two-stage reduce (smem reused).
// ---------------------------------------------------------------------------
template<int K>
__global__ __launch_bounds__(256, 4) void deform_mfma_k(
    const u16x8* __restrict__ hp8,
    const _Float16* __restrict__ om,
    const f16x8* __restrict__ wtb,
    _Float16* __restrict__ out)
{
    constexpr int PAD = K/2;
    constexpr int KK  = K*K;
    constexpr int NSB = HW/16;          // 2304 strips per batch
    constexpr int OMW = 3*KK*16;        // om slice elems
    constexpr int RED = 2*64*16;        // reduce buffer floats
    constexpr int SMEM = (OMW > RED ? OMW : RED);
    constexpr int HWW = K + 2;          // window rows
    constexpr int WWW = 16 + K + 2;     // window cols
    constexpr int WELEMS = 8*HWW*WWW;   // u16x8 elements

    __shared__ float smem[SMEM];
    __shared__ u16x8 win[8][HWW][WWW];

    int raw = blockIdx.x;               // [0, BB*NSB) = 4608
    int swz = (raw & 7)*((BB*NSB) >> 3) + (raw >> 3);
    int b = swz / NSB, strip = swz - b*NSB;

    int tid  = threadIdx.x;
    int wave = tid >> 6;
    int l    = tid & 63;
    int lg   = l >> 4;
    int lr   = l & 15;
    int th   = wave & 1;                // tap half
    int kkh  = wave >> 1;               // K-chunk half
    int pxbase = strip*16;
    int px   = pxbase + lr;
    int y    = px / WW, x = px - y*WW;  // y uniform per block (192%16==0)
    int x0   = pxbase - y*WW;

    int wy0 = y  + HALO - PAD - 1;      // window origin (padded coords)
    int wx0 = x0 + HALO - PAD - 1;

    // ---- stage window: all 8 channel-groups, clamped addresses ----
    {
        const u16x8* hbb = hp8 + (size_t)(b*8)*PLANE;
        for (int idx = tid; idx < WELEMS; idx += 256) {
            int g  = idx / (HWW*WWW);
            int r2 = idx - g*(HWW*WWW);
            int r  = r2 / WWW;
            int c2 = r2 - r*WWW;
            int gy = min(max(wy0 + r, 0), HP-1);
            int gx = min(max(wx0 + c2, 0), WP-1);
            win[g][r][c2] = hbb[(size_t)g*PLANE + gy*WP + gx];
        }
    }
    // ---- bulk om stage: [3KK][16] slice (f16 -> f32 in LDS) ----
    {
        const _Float16* ob = om + (size_t)b*3*KK*HW + pxbase;
        for (int idx = tid; idx < OMW; idx += 256) {
            int ch = idx >> 4, pl = idx & 15;
            smem[idx] = (float)ob[(size_t)ch*HW + pl];
        }
    }
    __syncthreads();

    int t0 = (KK*th)/2, t1 = (KK*(th+1))/2;

    f32x4 acc[4];
    #pragma unroll
    for (int ot = 0; ot < 4; ot++) acc[ot] = (f32x4)0.f;

    // global fallback base: this wave+lane's channel-group plane
    const u16x8* hb = hp8 + (size_t)(b*8 + kkh*4 + lg)*PLANE;
    int grp = kkh*4 + lg;

    #pragma unroll 1
    for (int t = t0; t < t1; t++) {
        int i = t / K, j = t - (t/K)*K;
        float offy = smem[(2*t  )*16 + lr];
        float offx = smem[(2*t+1)*16 + lr];
        float mk   = smem[(2*KK+t)*16 + lr];

        float py = (float)(y - PAD + i) + offy;
        float pxf= (float)(x - PAD + j) + offx;
        float fy = floorf(py), fx = floorf(pxf);
        float wy1 = py - fy, wx1 = pxf - fx;
        float wy0f = 1.f - wy1, wx0f = 1.f - wx1;
        int iy0 = (int)fy, ix0 = (int)fx;

        // clamp to [-1,192]: clamped loads land in the zero halo.
        int Y0 = min(max(iy0, -1), HH) + HALO;   // [2,195]
        int X0 = min(max(ix0, -1), WW) + HALO;   // [2,195]

        _Float16 h00 = (_Float16)(wy0f*wx0f*mk);
        _Float16 h01 = (_Float16)(wy0f*wx1*mk);
        _Float16 h10 = (_Float16)(wy1*wx0f*mk);
        _Float16 h11 = (_Float16)(wy1*wx1*mk);

        int ry = Y0 - wy0, rx = X0 - wx0;
        bool in = ((unsigned)ry <= (unsigned)(HWW-2)) &
                  ((unsigned)rx <= (unsigned)(WWW-2));

        f16x8 c0, c1, c2, c3;
        if (__all(in)) {
            const u16x8* Wp = &win[grp][ry][rx];
            c0 = __builtin_bit_cast(f16x8, Wp[0]);
            c1 = __builtin_bit_cast(f16x8, Wp[1]);
            c2 = __builtin_bit_cast(f16x8, Wp[WWW]);
            c3 = __builtin_bit_cast(f16x8, Wp[WWW+1]);
        } else {
            const u16x8* G = hb + (size_t)(Y0*WP + X0);
            c0 = __builtin_bit_cast(f16x8, G[0]);
            c1 = __builtin_bit_cast(f16x8, G[1]);
            c2 = __builtin_bit_cast(f16x8, G[WP]);
            c3 = __builtin_bit_cast(f16x8, G[WP+1]);
        }

        // packed fp16 bilinear blend -> A-fragment directly
        f16x8 s = c0*h00 + c1*h01 + c2*h10 + c3*h11;

        const f16x8* bp = wtb + (size_t)t*8*64 + l;
        #pragma unroll
        for (int ot = 0; ot < 4; ot++) {
            acc[ot] = __builtin_amdgcn_mfma_f32_16x16x32_f16(
                s, bp[(size_t)(kkh*4 + ot)*64], acc[ot], 0, 0, 0);
        }
    }

    // ---- two-stage reduce: kkh pairs, then th pairs (smem reused) ----
    __syncthreads();   // all waves done reading om slice
    float (*red)[64][16] = (float (*)[64][16])smem;   // [th][o][px]
    if (kkh == 1) {
        #pragma unroll
        for (int ot = 0; ot < 4; ot++)
            *reinterpret_cast<f32x4*>(&red[th][ot*16 + lr][lg*4]) = acc[ot];
    }
    __syncthreads();
    if (kkh == 0) {
        #pragma unroll
        for (int ot = 0; ot < 4; ot++)
            acc[ot] += *reinterpret_cast<const f32x4*>(&red[th][ot*16 + lr][lg*4]);
    }
    __syncthreads();
    if (kkh == 0 && th == 1) {
        #pragma unroll
        for (int ot = 0; ot < 4; ot++)
            *reinterpret_cast<f32x4*>(&red[0][ot*16 + lr][lg*4]) = acc[ot];
    }
    __syncthreads();
    if (kkh == 0 && th == 0) {
        _Float16* ob = out + (size_t)b*CC*HW + pxbase + lg*4;
        #pragma unroll
        for (int ot = 0; ot < 4; ot++) {
            f32x4 rr = *reinterpret_cast<const f32x4*>(&red[0][ot*16 + lr][lg*4]);
            rr += acc[ot];
            f16x4 v;
            v[0] = (_Float16)rr[0]; v[1] = (_Float16)rr[1];
            v[2] = (_Float16)rr[2]; v[3] = (_Float16)rr[3];
            *reinterpret_cast<f16x4*>(ob + (size_t)(ot*16 + lr)*HW) = v;
        }
    }
}

// ---------------------------------------------------------------------------
// Launch. Workspace (bytes):
//   hp8: BB*8*PLANE*16B          = ~10.0 MB  (fp16 interleaved padded h)
//   om : BB*3*49*HW*2B           = ~21.7 MB  (f16)
//   aa/mm/sm/u : BB*CC*HW*2B each = ~9.4 MB each (f16)
//   wtb/wbg f16                  = ~1.4 MB
// ---------------------------------------------------------------------------
extern "C" void kernel_launch(void* const* d_in, const int* in_sizes, int n_in,
                              void* d_out, int out_size, void* d_ws, size_t ws_size,
                              hipStream_t stream)
{
    const float* x_max      = (const float*)d_in[0];
    const float* x_mid      = (const float*)d_in[1];
    const float* x_small    = (const float*)d_in[2];
    const float* w_pre_max  = (const float*)d_in[3];
    const float* w_off_max  = (const float*)d_in[4];
    const float* b_off_max  = (const float*)d_in[5];
    const float* w_mod_max  = (const float*)d_in[6];
    const float* b_mod_max  = (const float*)d_in[7];
    const float* w_reg_max  = (const float*)d_in[8];
    const float* w_pre_mid  = (const float*)d_in[9];
    const float* w_off_mid  = (const float*)d_in[10];
    const float* b_off_mid  = (const float*)d_in[11];
    const float* w_mod_mid  = (const float*)d_in[12];
    const float* b_mod_mid  = (const float*)d_in[13];
    const float* w_reg_mid  = (const float*)d_in[14];
    const float* w_pre_small= (const float*)d_in[15];
    const float* w_off_small= (const float*)d_in[16];
    const float* b_off_small= (const float*)d_in[17];
    const float* w_mod_small= (const float*)d_in[18];
    const float* b_mod_small= (const float*)d_in[19];
    const float* w_reg_small= (const float*)d_in[20];
    const float* w1         = (const float*)d_in[21];
    const float* w2         = (const float*)d_in[22];

    float* out = (float*)d_out;
    char*  ws  = (char*)d_ws;

    u16x8*    hp8 = (u16x8*)ws;                       ws += (size_t)BB*8*PLANE*16;
    _Float16* om  = (_Float16*)ws;                    ws += (size_t)BB*3*49*HW*2;
    _Float16* aa  = (_Float16*)ws;                    ws += (size_t)BB*CC*HW*2;
    _Float16* mm  = (_Float16*)ws;                    ws += (size_t)BB*CC*HW*2;
    _Float16* sm  = (_Float16*)ws;                    ws += (size_t)BB*CC*HW*2;
    _Float16* u   = (_Float16*)ws;                    ws += (size_t)BB*CC*HW*2;
    f16x8*    wtb = (f16x8*)ws;                       ws += (size_t)49*8*64*16;
    f16x8*    wbg = (f16x8*)ws;

    hipMemsetAsync(hp8, 0, (size_t)BB*8*PLANE*16, stream);

    const int npix_blocks = (BB*HW)/256;   // 288
    const int dfm_blocks  = BB*(HW/16);    // 4608

    const int off7_blocks = BB*(HW/128)*2; // MT=2, NS=2 -> 1152
    const int off5_blocks = BB*(HW/64);    // MT=1, NS=1 -> 1152
    const int off3_blocks = BB*(HW/128);   // MT=2, NS=1 -> 576

    // ---- max branch (K=7) -> aa (f16)
    conv1x1_k<0><<<dim3(npix_blocks,2), 256, 0, stream>>>(x_max, nullptr, w_pre_max,
                                                  nullptr, nullptr, nullptr, hp8);
    make_woffb_k<7><<<49, 256, 0, stream>>>(w_off_max, w_mod_max, wbg);
    offmod_mfma_k<7,2,2,2><<<off7_blocks, 256, 0, stream>>>(hp8, wbg, b_off_max, b_mod_max, om);
    make_wtb_k<7><<<49, 512, 0, stream>>>(w_reg_max, wtb);
    deform_mfma_k<7><<<dfm_blocks, 256, 0, stream>>>(hp8, om, wtb, aa);

    // ---- mid branch (K=5) -> mm (f16)
    conv1x1_k<0><<<dim3(npix_blocks,2), 256, 0, stream>>>(x_mid, nullptr, w_pre_mid,
                                                  nullptr, nullptr, nullptr, hp8);
    make_woffb_k<5><<<25, 256, 0, stream>>>(w_off_mid, w_mod_mid, wbg);
    offmod_mfma_k<5,1,1,2><<<off5_blocks, 256, 0, stream>>>(hp8, wbg, b_off_mid, b_mod_mid, om);
    make_wtb_k<5><<<25, 512, 0, stream>>>(w_reg_mid, wtb);
    deform_mfma_k<5><<<dfm_blocks, 256, 0, stream>>>(hp8, om, wtb, mm);

    // ---- small branch (K=3) -> sm (f16)
    conv1x1_k<0><<<dim3(npix_blocks,2), 256, 0, stream>>>(x_small, nullptr, w_pre_small,
                                                  nullptr, nullptr, nullptr, hp8);
    make_woffb_k<3><<<9, 256, 0, stream>>>(w_off_small, w_mod_small, wbg);
    offmod_mfma_k<3,2,1,3><<<off3_blocks, 256, 0, stream>>>(hp8, wbg, b_off_small, b_mod_small, om);
    make_wtb_k<3><<<9, 512, 0, stream>>>(w_reg_small, wtb);
    deform_mfma_k<3><<<dfm_blocks, 256, 0, stream>>>(hp8, om, wtb, sm);

    // ---- combine (f16 in, f16 mid, f32 final)
    conv1x1_k<1><<<dim3(npix_blocks,2), 256, 0, stream>>>(aa, mm, w1,
                                                  nullptr, nullptr, nullptr, u);
    conv1x1_k<2><<<dim3(npix_blocks,2), 256, 0, stream>>>(u, sm, w2,
                                                  x_max, x_mid, x_small, out);
}

// Round 20
// 431.901 us; speedup vs baseline: 1.5029x; 1.2842x over previous
//
#include <hip/hip_runtime.h>
#include <hip/hip_bf16.h>
#include <math.h>

// Geometry (fixed by the reference)
#define BB   2
#define CC   64
#define HH   192
#define WW   192
#define HW   (HH*WW)          // 36864
#define HALO 3
#define HP   (HH + 2*HALO)    // 198
#define WP   (WW + 2*HALO)    // 198
#define PLANE (HP*WP)         // 39204

typedef __attribute__((ext_vector_type(8))) _Float16 f16x8;
typedef __attribute__((ext_vector_type(4))) _Float16 f16x4;
typedef __attribute__((ext_vector_type(8))) unsigned short u16x8;
typedef __attribute__((ext_vector_type(4))) float f32x4;

__device__ __forceinline__ float fast_tanh(float x) {
    float e = __expf(2.f * x);
    return 1.f - 2.f * __builtin_amdgcn_rcpf(e + 1.f);
}
__device__ __forceinline__ f16x8 bc16(u16x8 v) { return __builtin_bit_cast(f16x8, v); }

// ---------------------------------------------------------------------------
// Fused pre-conv: relu(Wz @ Xz) -> PADDED fp16 hp8 layout, branch z = blockIdx.z
// ---------------------------------------------------------------------------
__global__ __launch_bounds__(256) void conv_pre_k(
    const float* __restrict__ X0, const float* __restrict__ X1,
    const float* __restrict__ X2,
    const float* __restrict__ W0, const float* __restrict__ W1,
    const float* __restrict__ W2,
    u16x8* __restrict__ hp8all)
{
    __shared__ float wl[64*32];   // [c][o_half]
    int tid = threadIdx.x;
    int oh  = blockIdx.y;
    int z   = blockIdx.z;
    const float* X = (z == 0) ? X0 : ((z == 1) ? X1 : X2);
    const float* W = (z == 0) ? W0 : ((z == 1) ? W1 : W2);
    u16x8* hp8 = hp8all + (size_t)z * ((size_t)BB*8*PLANE);

    #pragma unroll
    for (int n = 0; n < 8; n++) {
        int idx = tid + n*256;
        int op  = idx >> 6, c = idx & 63;
        wl[c*32 + op] = W[(size_t)(oh*32 + op)*64 + c];
    }
    __syncthreads();

    int p  = blockIdx.x*256 + tid;
    int b  = p / HW;
    int pp = p - b*HW;
    size_t base = (size_t)b*CC*HW + pp;

    float acc[32];
    #pragma unroll
    for (int o = 0; o < 32; o++) acc[o] = 0.f;

    #pragma unroll 4
    for (int c = 0; c < 64; c++) {
        float xv = X[base + (size_t)c*HW];
        const float4* w4 = (const float4*)(wl + c*32);
        #pragma unroll
        for (int q = 0; q < 8; q++) {
            float4 w = w4[q];
            acc[4*q+0] = fmaf(w.x, xv, acc[4*q+0]);
            acc[4*q+1] = fmaf(w.y, xv, acc[4*q+1]);
            acc[4*q+2] = fmaf(w.z, xv, acc[4*q+2]);
            acc[4*q+3] = fmaf(w.w, xv, acc[4*q+3]);
        }
    }

    int y = pp / WW, x = pp - y*WW;
    #pragma unroll
    for (int gq = 0; gq < 4; gq++) {
        u16x8 v;
        #pragma unroll
        for (int c = 0; c < 8; c++)
            v[c] = __builtin_bit_cast(unsigned short,
                     (_Float16)fmaxf(acc[gq*8+c], 0.f));
        hp8[(size_t)(b*8 + oh*4 + gq)*PLANE + (size_t)(y+HALO)*WP + (x+HALO)] = v;
    }
}

// ---------------------------------------------------------------------------
// 1x1 conv combine stages (f16 in):
// MODE 1: relu(W@(X*tanh(M)))  -> flat f16
// MODE 2: relu(W@(X*tanh(M))) + Y0+Y1+Y2 -> flat f32 (d_out)
// ---------------------------------------------------------------------------
template<int MODE>
__global__ __launch_bounds__(256) void conv1x1_k(
    const _Float16* __restrict__ Xv, const _Float16* __restrict__ Mv,
    const float* __restrict__ W,
    const float* __restrict__ Y0, const float* __restrict__ Y1,
    const float* __restrict__ Y2,
    void* __restrict__ outv)
{
    __shared__ float wl[64*32];
    int tid = threadIdx.x;
    int oh  = blockIdx.y;
    #pragma unroll
    for (int n = 0; n < 8; n++) {
        int idx = tid + n*256;
        int op  = idx >> 6, c = idx & 63;
        wl[c*32 + op] = W[(size_t)(oh*32 + op)*64 + c];
    }
    __syncthreads();

    int p  = blockIdx.x*256 + tid;
    int b  = p / HW;
    int pp = p - b*HW;
    size_t base = (size_t)b*CC*HW + pp;

    float acc[32];
    #pragma unroll
    for (int o = 0; o < 32; o++) acc[o] = 0.f;

    #pragma unroll 4
    for (int c = 0; c < 64; c++) {
        float xv = (float)Xv[base + (size_t)c*HW];
        xv *= fast_tanh((float)Mv[base + (size_t)c*HW]);
        const float4* w4 = (const float4*)(wl + c*32);
        #pragma unroll
        for (int q = 0; q < 8; q++) {
            float4 w = w4[q];
            acc[4*q+0] = fmaf(w.x, xv, acc[4*q+0]);
            acc[4*q+1] = fmaf(w.y, xv, acc[4*q+1]);
            acc[4*q+2] = fmaf(w.z, xv, acc[4*q+2]);
            acc[4*q+3] = fmaf(w.w, xv, acc[4*q+3]);
        }
    }

    if (MODE == 1) {
        _Float16* op = (_Float16*)outv + base + (size_t)(oh*32)*HW;
        #pragma unroll
        for (int o = 0; o < 32; o++)
            op[(size_t)o*HW] = (_Float16)fmaxf(acc[o], 0.f);
    } else {
        float* op = (float*)outv + base + (size_t)(oh*32)*HW;
        size_t gi = base + (size_t)(oh*32)*HW;
        #pragma unroll
        for (int o = 0; o < 32; o++) {
            float yv = Y0[gi + (size_t)o*HW] + Y1[gi + (size_t)o*HW] + Y2[gi + (size_t)o*HW];
            op[(size_t)o*HW] = fmaxf(acc[o], 0.f) + yv;
        }
    }
}

// ---------------------------------------------------------------------------
// Weight baking (device helpers + single fused kernel, 83 blocks).
// ---------------------------------------------------------------------------
template<int K>
__device__ void bake_wtb_dev(const float* __restrict__ Wreg,
                             f16x8* __restrict__ wtb, int t, int tid)
{
    constexpr int KK = K*K;
    for (int e = tid; e < 512; e += 256) {
        int kk = e >> 8, rem = e & 255;
        int ot = rem >> 6, l = rem & 63;
        int lr = l & 15, lg = l >> 4;
        int o  = ot*16 + lr;
        f16x8 v;
        #pragma unroll
        for (int j = 0; j < 8; j++) {
            int c = kk*32 + lg*8 + j;
            v[j] = (_Float16)Wreg[((size_t)o*CC + c)*KK + t];
        }
        wtb[(size_t)t*512 + e] = v;
    }
}
template<int K>
__device__ void bake_wbg_dev(const float* __restrict__ Woff,
                             const float* __restrict__ Wmod,
                             f16x8* __restrict__ wbg, int pos, int tid)
{
    constexpr int KK  = K*K;
    constexpr int NTF = (3*KK + 15)/16;
    for (int idx = tid; idx < 2*NTF*64; idx += 256) {
        int kk  = idx / (NTF*64);
        int rem = idx - kk*(NTF*64);
        int nt  = rem >> 6;
        int l   = rem & 63;
        int lg  = l >> 4, lr = l & 15;
        int n   = nt*16 + lr;
        f16x8 v;
        #pragma unroll
        for (int j = 0; j < 8; j++) {
            int c = kk*32 + lg*8 + j;
            float w = 0.f;
            if (n < 2*KK)      w = Woff[((size_t)n*CC + c)*KK + pos];
            else if (n < 3*KK) w = Wmod[((size_t)(n - 2*KK)*CC + c)*KK + pos];
            v[j] = (_Float16)w;
        }
        wbg[(size_t)pos*(2*NTF*64) + idx] = v;
    }
}
__global__ __launch_bounds__(256) void bake_all_k(
    const float* wreg7, const float* woff7, const float* wmod7,
    const float* wreg5, const float* woff5, const float* wmod5,
    const float* wreg3, const float* woff3, const float* wmod3,
    f16x8* wtb7, f16x8* wbg7, f16x8* wtb5, f16x8* wbg5,
    f16x8* wtb3, f16x8* wbg3)
{
    int blk = blockIdx.x, tid = threadIdx.x;
    if (blk < 49) {
        bake_wtb_dev<7>(wreg7, wtb7, blk, tid);
        bake_wbg_dev<7>(woff7, wmod7, wbg7, blk, tid);
    } else if (blk < 74) {
        int p = blk - 49;
        bake_wtb_dev<5>(wreg5, wtb5, p, tid);
        bake_wbg_dev<5>(woff5, wmod5, wbg5, p, tid);
    } else {
        int p = blk - 74;
        bake_wtb_dev<3>(wreg3, wtb3, p, tid);
        bake_wbg_dev<3>(woff3, wmod3, wbg3, p, tid);
    }
}

// ---------------------------------------------------------------------------
// Offset + mask KxK conv as MFMA implicit GEMM (full conv), fp16, hp8 input.
// MT = M-tiles per wave; NS = n-split across blocks; PPR = positions/round.
// ---------------------------------------------------------------------------
template<int K, int MT, int NS, int PPR>
__global__ __launch_bounds__(256) void offmod_mfma_k(
    const u16x8* __restrict__ hp8,
    const f16x8* __restrict__ wbg,
    const float* __restrict__ Boff, const float* __restrict__ Bmod,
    _Float16* __restrict__ om)
{
    constexpr int PAD  = K/2;
    constexpr int KK   = K*K;
    constexpr int NTF  = (3*KK + 15)/16;
    constexpr int NT   = NTF/NS;
    constexpr int PBB  = HW/(64*MT);
    constexpr int NBLK = BB*PBB*NS;
    constexpr int ROUNDS = (KK + PPR - 1)/PPR;
    constexpr int WELEM  = PPR*2*NT*64;

    __shared__ f16x8 wl[WELEM];

    int raw = blockIdx.x;
    int swz = (raw & 7)*(NBLK >> 3) + (raw >> 3);
    int ng  = swz % NS;
    int s   = swz / NS;
    int b   = s / PBB;
    int blk = s - b*PBB;

    int tid  = threadIdx.x;
    int wave = tid >> 6;
    int l    = tid & 63;
    int lg   = l >> 4, lr = l & 15;
    int pxw  = blk*(4*MT*16) + wave*(MT*16);
    int y    = pxw / WW, x0 = pxw - y*WW;

    f32x4 acc[MT][NT];
    #pragma unroll
    for (int mt = 0; mt < MT; mt++)
        #pragma unroll
        for (int nt = 0; nt < NT; nt++) acc[mt][nt] = (f32x4)0.f;

    const u16x8* hb = hp8 + (size_t)(b*8)*PLANE;

    for (int r = 0; r < ROUNDS; r++) {
        __syncthreads();
        #pragma unroll
        for (int ii = 0; ii < (WELEM + 255)/256; ii++) {
            int idx = tid + ii*256;
            if (WELEM % 256 == 0 || idx < WELEM) {
                int pp  = idx / (2*NT*64);
                int rem = idx - pp*(2*NT*64);
                int kk  = rem / (NT*64);
                int rem2= rem - kk*(NT*64);
                int nt  = rem2 >> 6;
                int ll  = rem2 & 63;
                int pos = r*PPR + pp;
                if (pos < KK)
                    wl[idx] = wbg[(size_t)pos*(2*NTF*64)
                                  + (size_t)(kk*NTF + ng*NT + nt)*64 + ll];
            }
        }
        __syncthreads();

        #pragma unroll
        for (int pp = 0; pp < PPR; pp++) {
            int pos = r*PPR + pp;
            if (pos >= KK) break;
            int i = pos / K, j = pos - (pos/K)*K;
            int rbase = (y + HALO - PAD + i)*WP + (x0 + HALO - PAD + j);

            #pragma unroll
            for (int kk = 0; kk < 2; kk++) {
                const f16x8* G = (const f16x8*)(hb + (size_t)(kk*4 + lg)*PLANE + rbase);
                f16x8 a[MT];
                #pragma unroll
                for (int mt = 0; mt < MT; mt++) a[mt] = G[mt*16 + lr];
                #pragma unroll
                for (int nt = 0; nt < NT; nt++) {
                    f16x8 bf = wl[((pp*2 + kk)*NT + nt)*64 + l];
                    #pragma unroll
                    for (int mt = 0; mt < MT; mt++)
                        acc[mt][nt] = __builtin_amdgcn_mfma_f32_16x16x32_f16(
                            a[mt], bf, acc[mt][nt], 0, 0, 0);
                }
            }
        }
    }

    #pragma unroll
    for (int nt = 0; nt < NT; nt++) {
        int n = ng*NT*16 + nt*16 + lr;
        if (n < 3*KK) {
            bool is_mask = (n >= 2*KK);
            float bias = is_mask ? Bmod[n - 2*KK] : Boff[n];
            _Float16* dst0 = om + ((size_t)b*3*KK + n)*HW + pxw + lg*4;
            #pragma unroll
            for (int mt = 0; mt < MT; mt++) {
                f32x4 v = acc[mt][nt];
                float v0 = v[0] + bias, v1 = v[1] + bias, v2 = v[2] + bias, v3 = v[3] + bias;
                if (is_mask) {
                    v0 = 2.f * __builtin_amdgcn_rcpf(1.f + __expf(-v0));
                    v1 = 2.f * __builtin_amdgcn_rcpf(1.f + __expf(-v1));
                    v2 = 2.f * __builtin_amdgcn_rcpf(1.f + __expf(-v2));
                    v3 = 2.f * __builtin_amdgcn_rcpf(1.f + __expf(-v3));
                }
                f16x4 o;
                o[0] = (_Float16)v0; o[1] = (_Float16)v1;
                o[2] = (_Float16)v2; o[3] = (_Float16)v3;
                *reinterpret_cast<f16x4*>(dst0 + mt*16) = o;
            }
        }
    }
}

// ---------------------------------------------------------------------------
// Deformable sampling + MFMA channel matmul, fp16 hp8 input.
// r20: coords PRECOMPUTED once per block into LDS SoA {f16x4 weights,
// window offset+flag (u16), global offset (u32)} — removes the kkh-
// duplicated per-tap coordinate VALU. Tap loop: 2 small ds_reads + 4
// window ds_read_b128 + packed blend + 4 MFMA. Window staged in LDS with
// wave-uniform __all(in) fallback to global gathers (correct for any
// offsets). Reduce buffer XOR-swizzled (lg ^= o&3) to kill bank camping.
// Coord SoA and reduce buffer share one union region.
// ---------------------------------------------------------------------------
template<int K>
__global__ __launch_bounds__(256, 4) void deform_mfma_k(
    const u16x8* __restrict__ hp8,
    const _Float16* __restrict__ om,
    const f16x8* __restrict__ wtb,
    _Float16* __restrict__ out)
{
    constexpr int PAD = K/2;
    constexpr int KK  = K*K;
    constexpr int NSB = HW/16;
    constexpr int HWW = K + 2;
    constexpr int WWW = 16 + K + 2;
    constexpr int WELEMS = 8*HWW*WWW;
    constexpr int NPT = KK*16;
    constexpr int COORD_B = NPT*8 + NPT*4 + ((NPT*2 + 15)/16)*16;
    constexpr int RED_B   = 2*64*16*4;
    constexpr int UNION_B = (COORD_B > RED_B ? COORD_B : RED_B);

    __shared__ u16x8 win[8][HWW][WWW];
    __shared__ __align__(16) char ubuf[UNION_B];

    f16x4*          hco  = (f16x4*)ubuf;
    unsigned*       gofs = (unsigned*)(ubuf + NPT*8);
    unsigned short* wofs = (unsigned short*)(ubuf + NPT*8 + NPT*4);

    int raw = blockIdx.x;
    int swz = (raw & 7)*((BB*NSB) >> 3) + (raw >> 3);
    int b = swz / NSB, strip = swz - b*NSB;

    int tid  = threadIdx.x;
    int wave = tid >> 6;
    int l    = tid & 63;
    int lg   = l >> 4;
    int lr   = l & 15;
    int th   = wave & 1;
    int kkh  = wave >> 1;
    int pxbase = strip*16;
    int y    = pxbase / WW;               // uniform: 192 % 16 == 0
    int xs   = pxbase - y*WW;

    int wy0 = y  + HALO - PAD - 1;
    int wx0 = xs + HALO - PAD - 1;

    // ---- stage window (all 8 channel-groups, clamped) ----
    {
        const u16x8* hbb = hp8 + (size_t)(b*8)*PLANE;
        for (int idx = tid; idx < WELEMS; idx += 256) {
            int g  = idx / (HWW*WWW);
            int r2 = idx - g*(HWW*WWW);
            int r  = r2 / WWW;
            int c2 = r2 - r*WWW;
            int gy = min(max(wy0 + r, 0), HP-1);
            int gx = min(max(wx0 + c2, 0), WP-1);
            win[g][r][c2] = hbb[(size_t)g*PLANE + gy*WP + gx];
        }
    }
    // ---- precompute coords for all (px, tap) pairs ----
    {
        const _Float16* ob = om + (size_t)b*3*KK*HW + pxbase;
        for (int idx = tid; idx < NPT; idx += 256) {
            int pxl = idx & 15, t = idx >> 4;
            float offy = (float)ob[(size_t)(2*t  )*HW + pxl];
            float offx = (float)ob[(size_t)(2*t+1)*HW + pxl];
            float mk   = (float)ob[(size_t)(2*KK+t)*HW + pxl];
            int i = t / K, j = t - (t/K)*K;
            float py  = (float)(y - PAD + i) + offy;
            float pxf = (float)(xs + pxl - PAD + j) + offx;
            float fy = floorf(py), fx = floorf(pxf);
            float wy1 = py - fy, wx1 = pxf - fx;
            int iy0 = (int)fy, ix0 = (int)fx;
            int Y0 = min(max(iy0, -1), HH) + HALO;   // zero-halo clamp
            int X0 = min(max(ix0, -1), WW) + HALO;
            int ry = Y0 - wy0, rx = X0 - wx0;
            bool in = ((unsigned)ry <= (unsigned)(HWW-2)) &
                      ((unsigned)rx <= (unsigned)(WWW-2));
            f16x4 h;
            h[0] = (_Float16)((1.f-wy1)*(1.f-wx1)*mk);
            h[1] = (_Float16)((1.f-wy1)*wx1*mk);
            h[2] = (_Float16)(wy1*(1.f-wx1)*mk);
            h[3] = (_Float16)(wy1*wx1*mk);
            hco[idx]  = h;
            gofs[idx] = (unsigned)(Y0*WP + X0);
            wofs[idx] = (unsigned short)((ry*WWW + rx) | (in ? 0 : 0x8000));
        }
    }
    __syncthreads();

    int t0 = (KK*th)/2, t1 = (KK*(th+1))/2;

    f32x4 acc[4];
    #pragma unroll
    for (int ot = 0; ot < 4; ot++) acc[ot] = (f32x4)0.f;

    const u16x8* hb   = hp8 + (size_t)(b*8 + kkh*4 + lg)*PLANE;
    const u16x8* wing = &win[kkh*4 + lg][0][0];

    #pragma unroll 1
    for (int t = t0; t < t1; t++) {
        int idx = t*16 + lr;
        f16x4 h = hco[idx];
        unsigned short wf = wofs[idx];
        bool in = (wf & 0x8000) == 0;

        f16x8 c0, c1, c2, c3;
        if (__all(in)) {
            const u16x8* Wp = wing + wf;
            c0 = bc16(Wp[0]);   c1 = bc16(Wp[1]);
            c2 = bc16(Wp[WWW]); c3 = bc16(Wp[WWW+1]);
        } else {
            const u16x8* G = hb + gofs[idx];
            c0 = bc16(G[0]);  c1 = bc16(G[1]);
            c2 = bc16(G[WP]); c3 = bc16(G[WP+1]);
        }

        f16x8 s = c0*h[0] + c1*h[1] + c2*h[2] + c3*h[3];

        const f16x8* bp = wtb + (size_t)t*8*64 + l;
        #pragma unroll
        for (int ot = 0; ot < 4; ot++) {
            acc[ot] = __builtin_amdgcn_mfma_f32_16x16x32_f16(
                s, bp[(size_t)(kkh*4 + ot)*64], acc[ot], 0, 0, 0);
        }
    }

    // ---- two-stage reduce, XOR-swizzled (ubuf reused) ----
    __syncthreads();
    float* redf = (float*)ubuf;   // logical [2][64][16] f32, swizzled px dim
    #define RIDX(tt, o, g)  (((tt)*64 + (o))*16 + (((g) ^ ((o) & 3)) * 4))
    if (kkh == 1) {
        #pragma unroll
        for (int ot = 0; ot < 4; ot++) {
            int o = ot*16 + lr;
            *reinterpret_cast<f32x4*>(&redf[RIDX(th, o, lg)]) = acc[ot];
        }
    }
    __syncthreads();
    if (kkh == 0) {
        #pragma unroll
        for (int ot = 0; ot < 4; ot++) {
            int o = ot*16 + lr;
            acc[ot] += *reinterpret_cast<const f32x4*>(&redf[RIDX(th, o, lg)]);
        }
    }
    __syncthreads();
    if (kkh == 0 && th == 1) {
        #pragma unroll
        for (int ot = 0; ot < 4; ot++) {
            int o = ot*16 + lr;
            *reinterpret_cast<f32x4*>(&redf[RIDX(0, o, lg)]) = acc[ot];
        }
    }
    __syncthreads();
    if (kkh == 0 && th == 0) {
        _Float16* ob = out + (size_t)b*CC*HW + pxbase + lg*4;
        #pragma unroll
        for (int ot = 0; ot < 4; ot++) {
            int o = ot*16 + lr;
            f32x4 rr = *reinterpret_cast<const f32x4*>(&redf[RIDX(0, o, lg)]);
            rr += acc[ot];
            f16x4 v;
            v[0] = (_Float16)rr[0]; v[1] = (_Float16)rr[1];
            v[2] = (_Float16)rr[2]; v[3] = (_Float16)rr[3];
            *reinterpret_cast<f16x4*>(ob + (size_t)o*HW) = v;
        }
    }
    #undef RIDX
}

// ---------------------------------------------------------------------------
// Launch. Workspace (bytes):
//   hp8 x3 branches : 3 * BB*8*PLANE*16B = ~30.1 MB  (fp16 padded h)
//   om : BB*3*49*HW*2B  = ~21.7 MB (f16)
//   aa/mm/sm/u : BB*CC*HW*2B each = ~9.4 MB each (f16)
//   wtb7/wbg7/wtb5/wbg5/wtb3/wbg3 : ~2.2 MB total
// 11 launches total (was 18).
// ---------------------------------------------------------------------------
extern "C" void kernel_launch(void* const* d_in, const int* in_sizes, int n_in,
                              void* d_out, int out_size, void* d_ws, size_t ws_size,
                              hipStream_t stream)
{
    const float* x_max      = (const float*)d_in[0];
    const float* x_mid      = (const float*)d_in[1];
    const float* x_small    = (const float*)d_in[2];
    const float* w_pre_max  = (const float*)d_in[3];
    const float* w_off_max  = (const float*)d_in[4];
    const float* b_off_max  = (const float*)d_in[5];
    const float* w_mod_max  = (const float*)d_in[6];
    const float* b_mod_max  = (const float*)d_in[7];
    const float* w_reg_max  = (const float*)d_in[8];
    const float* w_pre_mid  = (const float*)d_in[9];
    const float* w_off_mid  = (const float*)d_in[10];
    const float* b_off_mid  = (const float*)d_in[11];
    const float* w_mod_mid  = (const float*)d_in[12];
    const float* b_mod_mid  = (const float*)d_in[13];
    const float* w_reg_mid  = (const float*)d_in[14];
    const float* w_pre_small= (const float*)d_in[15];
    const float* w_off_small= (const float*)d_in[16];
    const float* b_off_small= (const float*)d_in[17];
    const float* w_mod_small= (const float*)d_in[18];
    const float* b_mod_small= (const float*)d_in[19];
    const float* w_reg_small= (const float*)d_in[20];
    const float* w1         = (const float*)d_in[21];
    const float* w2         = (const float*)d_in[22];

    float* out = (float*)d_out;
    char*  ws  = (char*)d_ws;

    const size_t HPB = (size_t)BB*8*PLANE;      // u16x8 elems per branch

    u16x8*    hp8 = (u16x8*)ws;                 ws += 3*HPB*16;
    _Float16* om  = (_Float16*)ws;              ws += (size_t)BB*3*49*HW*2;
    _Float16* aa  = (_Float16*)ws;              ws += (size_t)BB*CC*HW*2;
    _Float16* mm  = (_Float16*)ws;              ws += (size_t)BB*CC*HW*2;
    _Float16* sm  = (_Float16*)ws;              ws += (size_t)BB*CC*HW*2;
    _Float16* u   = (_Float16*)ws;              ws += (size_t)BB*CC*HW*2;
    f16x8*    wtb7= (f16x8*)ws;                 ws += (size_t)49*512*16;
    f16x8*    wbg7= (f16x8*)ws;                 ws += (size_t)49*2*10*64*16;
    f16x8*    wtb5= (f16x8*)ws;                 ws += (size_t)25*512*16;
    f16x8*    wbg5= (f16x8*)ws;                 ws += (size_t)25*2*5*64*16;
    f16x8*    wtb3= (f16x8*)ws;                 ws += (size_t)9*512*16;
    f16x8*    wbg3= (f16x8*)ws;

    hipMemsetAsync(hp8, 0, 3*HPB*16, stream);

    const int npix_blocks = (BB*HW)/256;   // 288
    const int dfm_blocks  = BB*(HW/16);    // 4608
    const int off7_blocks = BB*(HW/128)*2; // MT=2, NS=2 -> 1152
    const int off5_blocks = BB*(HW/64);    // MT=1, NS=1 -> 1152
    const int off3_blocks = BB*(HW/128);   // MT=2, NS=1 -> 576

    // weight bakes (one launch) + fused pre-convs (one launch)
    bake_all_k<<<83, 256, 0, stream>>>(
        w_reg_max, w_off_max, w_mod_max,
        w_reg_mid, w_off_mid, w_mod_mid,
        w_reg_small, w_off_small, w_mod_small,
        wtb7, wbg7, wtb5, wbg5, wtb3, wbg3);
    conv_pre_k<<<dim3(npix_blocks, 2, 3), 256, 0, stream>>>(
        x_max, x_mid, x_small, w_pre_max, w_pre_mid, w_pre_small, hp8);

    // ---- max branch (K=7) -> aa
    offmod_mfma_k<7,2,2,2><<<off7_blocks, 256, 0, stream>>>(
        hp8 + 0*HPB, wbg7, b_off_max, b_mod_max, om);
    deform_mfma_k<7><<<dfm_blocks, 256, 0, stream>>>(hp8 + 0*HPB, om, wtb7, aa);

    // ---- mid branch (K=5) -> mm
    offmod_mfma_k<5,1,1,2><<<off5_blocks, 256, 0, stream>>>(
        hp8 + 1*HPB, wbg5, b_off_mid, b_mod_mid, om);
    deform_mfma_k<5><<<dfm_blocks, 256, 0, stream>>>(hp8 + 1*HPB, om, wtb5, mm);

    // ---- small branch (K=3) -> sm
    offmod_mfma_k<3,2,1,3><<<off3_blocks, 256, 0, stream>>>(
        hp8 + 2*HPB, wbg3, b_off_small, b_mod_small, om);
    deform_mfma_k<3><<<dfm_blocks, 256, 0, stream>>>(hp8 + 2*HPB, om, wtb3, sm);

    // ---- combine
    conv1x1_k<1><<<dim3(npix_blocks,2), 256, 0, stream>>>(aa, mm, w1,
                                                  nullptr, nullptr, nullptr, u);
    conv1x1_k<2><<<dim3(npix_blocks,2), 256, 0, stream>>>(u, sm, w2,
                                                  x_max, x_mid, x_small, out);
}